// Round 8
// baseline (136.183 us; speedup 1.0000x reference)
//
#include <hip/hip_runtime.h>
#include <hip/hip_bf16.h>

#define N_NODES 20000
#define N_EDGES 300000
#define FDIM    268
#define KPAD    288   // K padded to 9*32 for mfma K-loop
#define NPAD    288   // N padded to 9*32
#define HPAD    272   // h1 row stride in bf16 (34 slots * 8)
#define HSLOTS  34    // HPAD/8
#define EPS     1e-3f
#define NB_SCAN ((N_NODES + 255) / 256)   // 79

typedef __attribute__((ext_vector_type(8))) short short8;
typedef __attribute__((ext_vector_type(4))) float f32x4;
typedef __attribute__((ext_vector_type(8))) unsigned short ushort8;

__device__ inline short f2bf(float f) {
    __hip_bfloat16 b = __float2bfloat16(f);   // RNE
    return *reinterpret_cast<short*>(&b);
}
__device__ inline float bf2f(unsigned short u) {
    return __uint_as_float(((unsigned int)u) << 16);
}

// ---------------- CSR build ----------------

__global__ void count_kernel(const int* __restrict__ col, int* __restrict__ counts) {
    int e = blockIdx.x * blockDim.x + threadIdx.x;
    if (e < N_EDGES) atomicAdd(&counts[col[e]], 1);
}

// stage 1: per-block exclusive scan (256 elems/block) -> offs (no base), block sums; dis
__global__ __launch_bounds__(256) void scan1_kernel(const int* __restrict__ counts,
                                                    int* __restrict__ offs,
                                                    int* __restrict__ bsums,
                                                    float* __restrict__ dis) {
    int t = threadIdx.x;
    int i = blockIdx.x * 256 + t;
    int c = (i < N_NODES) ? counts[i] : 0;
    int lane = t & 63, w = t >> 6;
    int v = c;
#pragma unroll
    for (int off = 1; off < 64; off <<= 1) {
        int u = __shfl_up(v, off);
        if (lane >= off) v += u;
    }
    __shared__ int wsum[4];
    if (lane == 63) wsum[w] = v;
    __syncthreads();
    int wbase = 0;
#pragma unroll
    for (int k = 0; k < 4; ++k) if (k < w) wbase += wsum[k];
    int incl = v + wbase;
    if (i < N_NODES) {
        offs[i] = incl - c;                         // block-local exclusive
        dis[i]  = rsqrtf((float)(c + 1));           // +1 self-loop
    }
    if (t == 255) bsums[blockIdx.x] = incl;         // block total (padding adds 0)
}

// stage 2 (merged): each block computes its own base from bsums, adds, inits cursor
__global__ __launch_bounds__(256) void scan3_kernel(const int* __restrict__ bsums,
                                                    int* __restrict__ offs,
                                                    int* __restrict__ cursor) {
    __shared__ int red[256];
    int t = threadIdx.x;
    int b = blockIdx.x;
    red[t] = (t < NB_SCAN && t < b) ? bsums[t] : 0;
    __syncthreads();
#pragma unroll
    for (int st = 128; st > 0; st >>= 1) {
        if (t < st) red[t] += red[t + st];
        __syncthreads();
    }
    int base = red[0];
    int i = b * 256 + t;
    if (i < N_NODES) {
        int o = offs[i] + base;
        offs[i] = o;
        cursor[i] = o;
    }
    if (b == NB_SCAN - 1 && t == 0) offs[N_NODES] = base + bsums[b];
}

__global__ void fill_kernel(const int* __restrict__ row, const int* __restrict__ col,
                            int* __restrict__ cursor, int* __restrict__ esrc) {
    int e = blockIdx.x * blockDim.x + threadIdx.x;
    if (e < N_EDGES) {
        int c = col[e];
        int p = atomicAdd(&cursor[c], 1);
        esrc[p] = row[e];
    }
}

// ---------------- W1 -> W1^T bf16, zero-padded [NPAD][KPAD] ----------------
__global__ void conv_w(const float* __restrict__ W1, unsigned short* __restrict__ wt) {
    int idx = blockIdx.x * blockDim.x + threadIdx.x;
    if (idx >= NPAD * KPAD) return;
    int n = idx / KPAD, k = idx - n * KPAD;
    float v = (n < FDIM && k < FDIM) ? W1[(size_t)k * FDIM + n] : 0.f;
    wt[idx] = (unsigned short)f2bf(v);
}

// ---------------- GEMM: h1b = bf16(x) @ bf16(W1), output bf16 [N_NODES][HPAD] ----------------
// wave computes 32x32 via 2x2 mfma_f32_16x16x32_bf16 frags; A read direct from fp32 x.
__global__ __launch_bounds__(256) void gemm_mfma(const float* __restrict__ x,
                                                 const unsigned short* __restrict__ wt,
                                                 unsigned short* __restrict__ h1b) {
    int wid = blockIdx.x * 4 + (threadIdx.x >> 6);
    int m_idx = wid / 9;                  // n fastest: 9 n-waves share the A m-strip
    int n_idx = wid - m_idx * 9;
    if (m_idx >= N_NODES / 32) return;
    int lane = threadIdx.x & 63;
    int lrow = lane & 15;
    int lkg  = lane >> 4;                 // k-group 0..3
    int m0 = m_idx * 32, n0 = n_idx * 32;

    f32x4 acc[2][2];
#pragma unroll
    for (int a = 0; a < 2; ++a)
#pragma unroll
        for (int b = 0; b < 2; ++b) acc[a][b] = (f32x4){0.f, 0.f, 0.f, 0.f};

    const float* xr0 = x + (size_t)(m0 + lrow) * FDIM;
    const float* xr1 = x + (size_t)(m0 + 16 + lrow) * FDIM;

#pragma unroll
    for (int k0 = 0; k0 < KPAD; k0 += 32) {
        const int kb = k0 + lkg * 8;
        short8 a0, a1;
#pragma unroll
        for (int j = 0; j < 8; ++j) {
            int k = kb + j;                         // k0 compile-time -> mask folds away
            float v0 = (k < FDIM) ? xr0[k] : 0.f;
            float v1 = (k < FDIM) ? xr1[k] : 0.f;
            a0[j] = f2bf(v0);
            a1[j] = f2bf(v1);
        }
        short8 b0 = *reinterpret_cast<const short8*>(wt + (size_t)(n0 + lrow) * KPAD + kb);
        short8 b1 = *reinterpret_cast<const short8*>(wt + (size_t)(n0 + 16 + lrow) * KPAD + kb);
        acc[0][0] = __builtin_amdgcn_mfma_f32_16x16x32_bf16(a0, b0, acc[0][0], 0, 0, 0);
        acc[0][1] = __builtin_amdgcn_mfma_f32_16x16x32_bf16(a0, b1, acc[0][1], 0, 0, 0);
        acc[1][0] = __builtin_amdgcn_mfma_f32_16x16x32_bf16(a1, b0, acc[1][0], 0, 0, 0);
        acc[1][1] = __builtin_amdgcn_mfma_f32_16x16x32_bf16(a1, b1, acc[1][1], 0, 0, 0);
    }

    // C/D layout: col = lane&15, row = (lane>>4)*4 + reg   [m89-verified]
#pragma unroll
    for (int mi = 0; mi < 2; ++mi)
#pragma unroll
        for (int ni = 0; ni < 2; ++ni) {
            int colg = n0 + ni * 16 + lrow;
            if (colg < HPAD) {
#pragma unroll
                for (int r = 0; r < 4; ++r) {
                    int rowg = m0 + mi * 16 + lkg * 4 + r;
                    h1b[(size_t)rowg * HPAD + colg] = (unsigned short)f2bf(acc[mi][ni][r]);
                }
            }
        }
}

// ---------------- agg1: pull-aggregate bf16 h1 + bias+relu+bn+relu + dot(W2) -> z ----------------
// one wave per node. Neighbor list pre-loaded coalesced; (src,w) via shfl.
// Uniform zero-padded loop (pad edges have w=0 -> exact +0) + software pipeline:
// next iteration's 4 rows prefetched before current iteration's FMA block.
__global__ __launch_bounds__(256) void agg1_kernel(const unsigned short* __restrict__ h1b,
                                                   const int* __restrict__ offs,
                                                   const int* __restrict__ esrc,
                                                   const float* __restrict__ dis,
                                                   const float* __restrict__ b1,
                                                   const float* __restrict__ g1,
                                                   const float* __restrict__ beta1,
                                                   const float* __restrict__ rm1,
                                                   const float* __restrict__ rv1,
                                                   const float* __restrict__ W2,
                                                   float* __restrict__ z) {
    int wave = blockIdx.x * 4 + (threadIdx.x >> 6);
    if (wave >= N_NODES) return;
    int lane = threadIdx.x & 63;
    int h  = lane >> 5;       // half 0/1
    int sl = lane & 31;       // slot 0..31 (features sl*8..sl*8+7)
    const int i = wave;
    const bool tl = (sl < 2);

    float a[8]  = {0.f, 0.f, 0.f, 0.f, 0.f, 0.f, 0.f, 0.f};
    float ta[8] = {0.f, 0.f, 0.f, 0.f, 0.f, 0.f, 0.f, 0.f};  // tail slots 32/33

    const ushort8* base = reinterpret_cast<const ushort8*>(h1b);
    const int s = offs[i], e = offs[i + 1];
    const int deg = e - s;
    const float di = dis[i];

    // self-loop (h==0 half only, via zero weight on h==1)
    {
        const float ws = (h == 0) ? di : 0.f;
        const ushort8* hr = base + (size_t)i * HSLOTS;
        ushort8 v = hr[sl];
#pragma unroll
        for (int j = 0; j < 8; ++j) a[j] += ws * bf2f(v[j]);
        if (tl) {
            ushort8 vt = hr[32 + sl];
#pragma unroll
            for (int j = 0; j < 8; ++j) ta[j] += ws * bf2f(vt[j]);
        }
    }

    for (int c0 = 0; c0 < deg; c0 += 64) {
        int cnt = deg - c0; if (cnt > 64) cnt = 64;
        int   lsrc = 0;
        float lw   = 0.f;
        if (lane < cnt) {
            lsrc = esrc[s + c0 + lane];    // coalesced
            lw   = dis[lsrc];
        }
        const int niter = (cnt + 7) >> 3;  // wave-uniform; pads contribute exact 0
        int p = h;
        // prologue: fetch rows for iteration 0
        int   s0 = __shfl(lsrc, p),     s1 = __shfl(lsrc, p + 2);
        int   s2 = __shfl(lsrc, p + 4), s3 = __shfl(lsrc, p + 6);
        float w0 = __shfl(lw, p),       w1 = __shfl(lw, p + 2);
        float w2 = __shfl(lw, p + 4),   w3 = __shfl(lw, p + 6);
        const ushort8* r0 = base + (size_t)s0 * HSLOTS;
        const ushort8* r1 = base + (size_t)s1 * HSLOTS;
        const ushort8* r2 = base + (size_t)s2 * HSLOTS;
        const ushort8* r3 = base + (size_t)s3 * HSLOTS;
        ushort8 v0 = r0[sl], v1 = r1[sl], v2 = r2[sl], v3 = r3[sl];
        ushort8 t0 = v0, t1 = v1, t2 = v2, t3 = v3;
        if (tl) { t0 = r0[32 + sl]; t1 = r1[32 + sl]; t2 = r2[32 + sl]; t3 = r3[32 + sl]; }

        for (int k = 1; k < niter; ++k) {
            // prefetch iteration k (register-only deps -> loads issue before FMAs)
            int np = h + k * 8;
            int   ns0 = __shfl(lsrc, np),     ns1 = __shfl(lsrc, np + 2);
            int   ns2 = __shfl(lsrc, np + 4), ns3 = __shfl(lsrc, np + 6);
            float nw0 = __shfl(lw, np),       nw1 = __shfl(lw, np + 2);
            float nw2 = __shfl(lw, np + 4),   nw3 = __shfl(lw, np + 6);
            const ushort8* q0 = base + (size_t)ns0 * HSLOTS;
            const ushort8* q1 = base + (size_t)ns1 * HSLOTS;
            const ushort8* q2 = base + (size_t)ns2 * HSLOTS;
            const ushort8* q3 = base + (size_t)ns3 * HSLOTS;
            ushort8 nv0 = q0[sl], nv1 = q1[sl], nv2 = q2[sl], nv3 = q3[sl];
            ushort8 nt0 = nv0, nt1 = nv1, nt2 = nv2, nt3 = nv3;
            if (tl) { nt0 = q0[32 + sl]; nt1 = q1[32 + sl]; nt2 = q2[32 + sl]; nt3 = q3[32 + sl]; }

            // compute iteration k-1
#pragma unroll
            for (int j = 0; j < 8; ++j)
                a[j] += w0 * bf2f(v0[j]) + w1 * bf2f(v1[j]) + w2 * bf2f(v2[j]) + w3 * bf2f(v3[j]);
            if (tl) {
#pragma unroll
                for (int j = 0; j < 8; ++j)
                    ta[j] += w0 * bf2f(t0[j]) + w1 * bf2f(t1[j]) + w2 * bf2f(t2[j]) + w3 * bf2f(t3[j]);
            }
            // rotate
            v0 = nv0; v1 = nv1; v2 = nv2; v3 = nv3;
            t0 = nt0; t1 = nt1; t2 = nt2; t3 = nt3;
            w0 = nw0; w1 = nw1; w2 = nw2; w3 = nw3;
        }
        // epilogue: last iteration's compute
#pragma unroll
        for (int j = 0; j < 8; ++j)
            a[j] += w0 * bf2f(v0[j]) + w1 * bf2f(v1[j]) + w2 * bf2f(v2[j]) + w3 * bf2f(v3[j]);
        if (tl) {
#pragma unroll
            for (int j = 0; j < 8; ++j)
                ta[j] += w0 * bf2f(t0[j]) + w1 * bf2f(t1[j]) + w2 * bf2f(t2[j]) + w3 * bf2f(t3[j]);
        }
    }

    // merge halves
#pragma unroll
    for (int j = 0; j < 8; ++j) a[j]  += __shfl_xor(a[j], 32);
#pragma unroll
    for (int j = 0; j < 8; ++j) ta[j] += __shfl_xor(ta[j], 32);

    float zp = 0.f;
    if (h == 0) {
        int f0 = sl * 8;
#pragma unroll
        for (int j = 0; j < 8; ++j) {
            int f = f0 + j;
            float v = fmaxf(di * a[j] + b1[f], 0.f);
            v = fmaxf((v - rm1[f]) * rsqrtf(rv1[f] + EPS) * g1[f] + beta1[f], 0.f);
            zp += v * W2[f];
        }
        if (tl) {
            int ft0 = 256 + sl * 8;
#pragma unroll
            for (int j = 0; j < 8; ++j) {
                int f = ft0 + j;
                if (f < FDIM) {
                    float v = fmaxf(di * ta[j] + b1[f], 0.f);
                    v = fmaxf((v - rm1[f]) * rsqrtf(rv1[f] + EPS) * g1[f] + beta1[f], 0.f);
                    zp += v * W2[f];
                }
            }
        }
    }
#pragma unroll
    for (int off = 32; off > 0; off >>= 1) zp += __shfl_xor(zp, off);
    if (lane == 0) z[i] = zp;
}

// ---------------- agg2: pull-aggregate z + bias + bn + relu + sigmoid -> out ----------------
__global__ void agg2_kernel(const float* __restrict__ z,
                            const int* __restrict__ offs,
                            const int* __restrict__ esrc,
                            const float* __restrict__ dis,
                            const float* __restrict__ b2,
                            const float* __restrict__ g2,
                            const float* __restrict__ beta2,
                            const float* __restrict__ rm2,
                            const float* __restrict__ rv2,
                            float* __restrict__ out) {
    int i = blockIdx.x * blockDim.x + threadIdx.x;
    if (i >= N_NODES) return;
    int s = offs[i], e = offs[i + 1];
    float acc = 0.f;
    int p = s;
    for (; p + 3 < e; p += 4) {   // 4 gathers in flight
        int s0 = esrc[p], s1 = esrc[p + 1], s2 = esrc[p + 2], s3 = esrc[p + 3];
        acc += dis[s0] * z[s0] + dis[s1] * z[s1] + dis[s2] * z[s2] + dis[s3] * z[s3];
    }
    for (; p < e; ++p) {
        int s0 = esrc[p];
        acc += dis[s0] * z[s0];
    }
    float di = dis[i];
    acc += di * z[i];                 // self loop
    float pre = di * acc + b2[0];
    float v = (pre - rm2[0]) * rsqrtf(rv2[0] + EPS) * g2[0] + beta2[0];
    v = fmaxf(v, 0.f);
    out[i] = 1.f / (1.f + expf(-v));
}

// ---------------- launcher ----------------
extern "C" void kernel_launch(void* const* d_in, const int* in_sizes, int n_in,
                              void* d_out, int out_size, void* d_ws, size_t ws_size,
                              hipStream_t stream) {
    const float* x     = (const float*)d_in[0];
    const int*   ei    = (const int*)d_in[1];     // [2, E]: row = ei, col = ei + E
    const float* W1    = (const float*)d_in[2];
    const float* b1    = (const float*)d_in[3];
    const float* g1    = (const float*)d_in[4];
    const float* beta1 = (const float*)d_in[5];
    const float* rm1   = (const float*)d_in[6];
    const float* rv1   = (const float*)d_in[7];
    const float* W2    = (const float*)d_in[8];
    const float* b2    = (const float*)d_in[9];
    const float* g2    = (const float*)d_in[10];
    const float* beta2 = (const float*)d_in[11];
    const float* rm2   = (const float*)d_in[12];
    const float* rv2   = (const float*)d_in[13];
    float* out = (float*)d_out;

    // workspace layout (~12.9 MB)
    unsigned short* wt  = (unsigned short*)d_ws;            // NPAD*KPAD
    unsigned short* h1b = wt + (size_t)NPAD * KPAD;         // N_NODES*HPAD
    float* z    = (float*)(h1b + (size_t)N_NODES * HPAD);
    float* dis  = z + N_NODES;
    int* counts = (int*)(dis + N_NODES);
    int* offs   = counts + N_NODES;
    int* cursor = offs + N_NODES + 1;
    int* esrc   = cursor + N_NODES;
    int* bsums  = esrc + N_EDGES;                           // NB_SCAN

    const int* row = ei;
    const int* col = ei + N_EDGES;

    hipMemsetAsync(counts, 0, N_NODES * sizeof(int), stream);

    int eb = (N_EDGES + 255) / 256;
    count_kernel<<<eb, 256, 0, stream>>>(col, counts);
    scan1_kernel<<<NB_SCAN, 256, 0, stream>>>(counts, offs, bsums, dis);
    scan3_kernel<<<NB_SCAN, 256, 0, stream>>>(bsums, offs, cursor);
    fill_kernel<<<eb, 256, 0, stream>>>(row, col, cursor, esrc);

    conv_w<<<(NPAD * KPAD + 255) / 256, 256, 0, stream>>>(W1, wt);

    int nwaves = (N_NODES / 32) * 9;                 // 5625
    gemm_mfma<<<(nwaves + 3) / 4, 256, 0, stream>>>(x, wt, h1b);

    agg1_kernel<<<(N_NODES + 3) / 4, 256, 0, stream>>>(h1b, offs, esrc, dis,
                                                       b1, g1, beta1, rm1, rv1, W2, z);
    agg2_kernel<<<(N_NODES + 255) / 256, 256, 0, stream>>>(z, offs, esrc, dis,
                                                           b2, g2, beta2, rm2, rv2, out);
}

// Round 9
// 126.959 us; speedup vs baseline: 1.0727x; 1.0727x over previous
//
#include <hip/hip_runtime.h>
#include <hip/hip_bf16.h>

#define N_NODES 20000
#define N_EDGES 300000
#define FDIM    268
#define KPAD    288   // K padded to 9*32 for mfma K-loop
#define NPAD    288   // N padded to 9*32
#define MCOLS   256   // main h1 row (bf16), 32 slots of 8
#define TCOLS   16    // tail h1 row (bf16), 2 slots (12 valid + 4 zero)
#define EPS     1e-3f
#define NB_SCAN ((N_NODES + 255) / 256)   // 79

typedef __attribute__((ext_vector_type(8))) short short8;
typedef __attribute__((ext_vector_type(4))) float f32x4;
typedef __attribute__((ext_vector_type(8))) unsigned short ushort8;

__device__ inline short f2bf(float f) {
    __hip_bfloat16 b = __float2bfloat16(f);   // RNE
    return *reinterpret_cast<short*>(&b);
}
__device__ inline float bf2f(unsigned short u) {
    return __uint_as_float(((unsigned int)u) << 16);
}

// ---------------- CSR build ----------------

__global__ void count_kernel(const int* __restrict__ col, int* __restrict__ counts) {
    int e = blockIdx.x * blockDim.x + threadIdx.x;
    if (e < N_EDGES) atomicAdd(&counts[col[e]], 1);
}

// stage 1: per-block exclusive scan (256 elems/block) -> offs (no base), block sums; dis
__global__ __launch_bounds__(256) void scan1_kernel(const int* __restrict__ counts,
                                                    int* __restrict__ offs,
                                                    int* __restrict__ bsums,
                                                    float* __restrict__ dis) {
    int t = threadIdx.x;
    int i = blockIdx.x * 256 + t;
    int c = (i < N_NODES) ? counts[i] : 0;
    int lane = t & 63, w = t >> 6;
    int v = c;
#pragma unroll
    for (int off = 1; off < 64; off <<= 1) {
        int u = __shfl_up(v, off);
        if (lane >= off) v += u;
    }
    __shared__ int wsum[4];
    if (lane == 63) wsum[w] = v;
    __syncthreads();
    int wbase = 0;
#pragma unroll
    for (int k = 0; k < 4; ++k) if (k < w) wbase += wsum[k];
    int incl = v + wbase;
    if (i < N_NODES) {
        offs[i] = incl - c;                         // block-local exclusive
        dis[i]  = rsqrtf((float)(c + 1));           // +1 self-loop
    }
    if (t == 255) bsums[blockIdx.x] = incl;         // block total (padding adds 0)
}

// stage 2 (merged): each block computes its own base from bsums, adds, inits cursor
__global__ __launch_bounds__(256) void scan3_kernel(const int* __restrict__ bsums,
                                                    int* __restrict__ offs,
                                                    int* __restrict__ cursor) {
    __shared__ int red[256];
    int t = threadIdx.x;
    int b = blockIdx.x;
    red[t] = (t < NB_SCAN && t < b) ? bsums[t] : 0;
    __syncthreads();
#pragma unroll
    for (int st = 128; st > 0; st >>= 1) {
        if (t < st) red[t] += red[t + st];
        __syncthreads();
    }
    int base = red[0];
    int i = b * 256 + t;
    if (i < N_NODES) {
        int o = offs[i] + base;
        offs[i] = o;
        cursor[i] = o;
    }
    if (b == NB_SCAN - 1 && t == 0) offs[N_NODES] = base + bsums[b];
}

__global__ void fill_kernel(const int* __restrict__ row, const int* __restrict__ col,
                            int* __restrict__ cursor, int* __restrict__ esrc) {
    int e = blockIdx.x * blockDim.x + threadIdx.x;
    if (e < N_EDGES) {
        int c = col[e];
        int p = atomicAdd(&cursor[c], 1);
        esrc[p] = row[e];
    }
}

// ---------------- W1 -> W1^T bf16, zero-padded [NPAD][KPAD] ----------------
__global__ void conv_w(const float* __restrict__ W1, unsigned short* __restrict__ wt) {
    int idx = blockIdx.x * blockDim.x + threadIdx.x;
    if (idx >= NPAD * KPAD) return;
    int n = idx / KPAD, k = idx - n * KPAD;
    float v = (n < FDIM && k < FDIM) ? W1[(size_t)k * FDIM + n] : 0.f;
    wt[idx] = (unsigned short)f2bf(v);
}

// ---------------- GEMM: bf16(x) @ bf16(W1) -> h1main [N][256] + h1t [N][16] ----------------
__global__ __launch_bounds__(256) void gemm_mfma(const float* __restrict__ x,
                                                 const unsigned short* __restrict__ wt,
                                                 unsigned short* __restrict__ h1main,
                                                 unsigned short* __restrict__ h1t) {
    int wid = blockIdx.x * 4 + (threadIdx.x >> 6);
    int m_idx = wid / 9;                  // n fastest: 9 n-waves share the A m-strip
    int n_idx = wid - m_idx * 9;
    if (m_idx >= N_NODES / 32) return;
    int lane = threadIdx.x & 63;
    int lrow = lane & 15;
    int lkg  = lane >> 4;                 // k-group 0..3
    int m0 = m_idx * 32, n0 = n_idx * 32;

    f32x4 acc[2][2];
#pragma unroll
    for (int a = 0; a < 2; ++a)
#pragma unroll
        for (int b = 0; b < 2; ++b) acc[a][b] = (f32x4){0.f, 0.f, 0.f, 0.f};

    const float* xr0 = x + (size_t)(m0 + lrow) * FDIM;
    const float* xr1 = x + (size_t)(m0 + 16 + lrow) * FDIM;

#pragma unroll
    for (int k0 = 0; k0 < KPAD; k0 += 32) {
        const int kb = k0 + lkg * 8;
        short8 a0, a1;
#pragma unroll
        for (int j = 0; j < 8; ++j) {
            int k = kb + j;                         // k0 compile-time -> mask folds away
            float v0 = (k < FDIM) ? xr0[k] : 0.f;
            float v1 = (k < FDIM) ? xr1[k] : 0.f;
            a0[j] = f2bf(v0);
            a1[j] = f2bf(v1);
        }
        short8 b0 = *reinterpret_cast<const short8*>(wt + (size_t)(n0 + lrow) * KPAD + kb);
        short8 b1 = *reinterpret_cast<const short8*>(wt + (size_t)(n0 + 16 + lrow) * KPAD + kb);
        acc[0][0] = __builtin_amdgcn_mfma_f32_16x16x32_bf16(a0, b0, acc[0][0], 0, 0, 0);
        acc[0][1] = __builtin_amdgcn_mfma_f32_16x16x32_bf16(a0, b1, acc[0][1], 0, 0, 0);
        acc[1][0] = __builtin_amdgcn_mfma_f32_16x16x32_bf16(a1, b0, acc[1][0], 0, 0, 0);
        acc[1][1] = __builtin_amdgcn_mfma_f32_16x16x32_bf16(a1, b1, acc[1][1], 0, 0, 0);
    }

    // C/D layout: col = lane&15, row = (lane>>4)*4 + reg   [m89-verified]
#pragma unroll
    for (int mi = 0; mi < 2; ++mi)
#pragma unroll
        for (int ni = 0; ni < 2; ++ni) {
            int colg = n0 + ni * 16 + lrow;
#pragma unroll
            for (int r = 0; r < 4; ++r) {
                int rowg = m0 + mi * 16 + lkg * 4 + r;
                unsigned short hv = (unsigned short)f2bf(acc[mi][ni][r]);
                if (colg < MCOLS) {
                    h1main[(size_t)rowg * MCOLS + colg] = hv;
                } else if (colg < MCOLS + TCOLS) {
                    h1t[(size_t)rowg * TCOLS + (colg - MCOLS)] = hv;
                }
            }
        }
}

// ---------------- agg1: pull-aggregate + bias+relu+bn+relu + dot(W2) -> z ----------------
// grid-stride over nodes, one wave per node.
// Main (256 feats): half-wave (32 lanes x 16B) per row, 4 loads / 8 edges, zero-padded uniform loop.
// Tail (12 feats): all 64 lanes, lane l -> edge (l>>1), slot (l&1), from compact L2-resident h1t.
__global__ __launch_bounds__(256) void agg1_kernel(const unsigned short* __restrict__ h1main,
                                                   const unsigned short* __restrict__ h1t,
                                                   const int* __restrict__ offs,
                                                   const int* __restrict__ esrc,
                                                   const float* __restrict__ dis,
                                                   const float* __restrict__ b1,
                                                   const float* __restrict__ g1,
                                                   const float* __restrict__ beta1,
                                                   const float* __restrict__ rm1,
                                                   const float* __restrict__ rv1,
                                                   const float* __restrict__ W2,
                                                   float* __restrict__ z) {
    const int lane = threadIdx.x & 63;
    const int h  = lane >> 5;       // half 0/1
    const int sl = lane & 31;       // slot 0..31 (features sl*8..sl*8+7)
    const int wave0 = blockIdx.x * 4 + (threadIdx.x >> 6);
    const int wstride = gridDim.x * 4;
    const ushort8* mbase = reinterpret_cast<const ushort8*>(h1main);
    const ushort8* tbase = reinterpret_cast<const ushort8*>(h1t);

    for (int i = wave0; i < N_NODES; i += wstride) {
        float a[8]  = {0.f, 0.f, 0.f, 0.f, 0.f, 0.f, 0.f, 0.f};
        float tb[8] = {0.f, 0.f, 0.f, 0.f, 0.f, 0.f, 0.f, 0.f};

        const int s = offs[i], e = offs[i + 1];
        const int deg = e - s;
        const float di = dis[i];

        // self-loop main (h==0 half carries weight di, h==1 adds exact 0)
        {
            const float ws = (h == 0) ? di : 0.f;
            ushort8 v = mbase[(size_t)i * 32 + sl];
#pragma unroll
            for (int j = 0; j < 8; ++j) a[j] += ws * bf2f(v[j]);
        }
        // self-loop tail (lanes 0,1 -> slots 0,1)
        if (lane < 2) {
            ushort8 v = tbase[(size_t)i * 2 + lane];
#pragma unroll
            for (int j = 0; j < 8; ++j) tb[j] += di * bf2f(v[j]);
        }

        for (int c0 = 0; c0 < deg; c0 += 64) {
            int cnt = deg - c0; if (cnt > 64) cnt = 64;
            int   lsrc = 0;
            float lw   = 0.f;
            if (lane < cnt) {
                lsrc = esrc[s + c0 + lane];    // coalesced
                lw   = dis[lsrc];
            }
            // ---- main: 8 edges/iter (4 per half), pads contribute exact 0 ----
            const int niter = (cnt + 7) >> 3;
            for (int k = 0; k < niter; ++k) {
                int p = h + k * 8;
                int   s0 = __shfl(lsrc, p),     s1 = __shfl(lsrc, p + 2);
                int   s2 = __shfl(lsrc, p + 4), s3 = __shfl(lsrc, p + 6);
                float w0 = __shfl(lw, p),       w1 = __shfl(lw, p + 2);
                float w2 = __shfl(lw, p + 4),   w3 = __shfl(lw, p + 6);
                ushort8 v0 = mbase[(size_t)s0 * 32 + sl];
                ushort8 v1 = mbase[(size_t)s1 * 32 + sl];
                ushort8 v2 = mbase[(size_t)s2 * 32 + sl];
                ushort8 v3 = mbase[(size_t)s3 * 32 + sl];
#pragma unroll
                for (int j = 0; j < 8; ++j)
                    a[j] += w0 * bf2f(v0[j]) + w1 * bf2f(v1[j]) + w2 * bf2f(v2[j]) + w3 * bf2f(v3[j]);
            }
            // ---- tail: 32 edges/iter, lane l -> edge (l>>1), slot (l&1) ----
            const int tniter = (cnt + 31) >> 5;
            for (int k = 0; k < tniter; ++k) {
                int ei = k * 32 + (lane >> 1);
                int   ts = __shfl(lsrc, ei);
                float tw = __shfl(lw, ei);
                ushort8 v = tbase[(size_t)ts * 2 + (lane & 1)];
#pragma unroll
                for (int j = 0; j < 8; ++j) tb[j] += tw * bf2f(v[j]);
            }
        }

        // merge halves (main)
#pragma unroll
        for (int j = 0; j < 8; ++j) a[j] += __shfl_xor(a[j], 32);
        // reduce tail across lanes sharing (lane&1)
#pragma unroll
        for (int j = 0; j < 8; ++j) {
            tb[j] += __shfl_xor(tb[j], 2);
            tb[j] += __shfl_xor(tb[j], 4);
            tb[j] += __shfl_xor(tb[j], 8);
            tb[j] += __shfl_xor(tb[j], 16);
            tb[j] += __shfl_xor(tb[j], 32);
        }

        float zp = 0.f;
        if (h == 0) {
            int f0 = sl * 8;
#pragma unroll
            for (int j = 0; j < 8; ++j) {
                int f = f0 + j;
                float v = fmaxf(di * a[j] + b1[f], 0.f);
                v = fmaxf((v - rm1[f]) * rsqrtf(rv1[f] + EPS) * g1[f] + beta1[f], 0.f);
                zp += v * W2[f];
            }
            if (sl < 2) {
                int ft0 = 256 + sl * 8;
#pragma unroll
                for (int j = 0; j < 8; ++j) {
                    int f = ft0 + j;
                    if (f < FDIM) {
                        float v = fmaxf(di * tb[j] + b1[f], 0.f);
                        v = fmaxf((v - rm1[f]) * rsqrtf(rv1[f] + EPS) * g1[f] + beta1[f], 0.f);
                        zp += v * W2[f];
                    }
                }
            }
        }
#pragma unroll
        for (int off = 32; off > 0; off >>= 1) zp += __shfl_xor(zp, off);
        if (lane == 0) z[i] = zp;
    }
}

// ---------------- agg2: pull-aggregate z + bias + bn + relu + sigmoid -> out ----------------
__global__ void agg2_kernel(const float* __restrict__ z,
                            const int* __restrict__ offs,
                            const int* __restrict__ esrc,
                            const float* __restrict__ dis,
                            const float* __restrict__ b2,
                            const float* __restrict__ g2,
                            const float* __restrict__ beta2,
                            const float* __restrict__ rm2,
                            const float* __restrict__ rv2,
                            float* __restrict__ out) {
    int i = blockIdx.x * blockDim.x + threadIdx.x;
    if (i >= N_NODES) return;
    int s = offs[i], e = offs[i + 1];
    float acc = 0.f;
    int p = s;
    for (; p + 3 < e; p += 4) {   // 4 gathers in flight
        int s0 = esrc[p], s1 = esrc[p + 1], s2 = esrc[p + 2], s3 = esrc[p + 3];
        acc += dis[s0] * z[s0] + dis[s1] * z[s1] + dis[s2] * z[s2] + dis[s3] * z[s3];
    }
    for (; p < e; ++p) {
        int s0 = esrc[p];
        acc += dis[s0] * z[s0];
    }
    float di = dis[i];
    acc += di * z[i];                 // self loop
    float pre = di * acc + b2[0];
    float v = (pre - rm2[0]) * rsqrtf(rv2[0] + EPS) * g2[0] + beta2[0];
    v = fmaxf(v, 0.f);
    out[i] = 1.f / (1.f + expf(-v));
}

// ---------------- launcher ----------------
extern "C" void kernel_launch(void* const* d_in, const int* in_sizes, int n_in,
                              void* d_out, int out_size, void* d_ws, size_t ws_size,
                              hipStream_t stream) {
    const float* x     = (const float*)d_in[0];
    const int*   ei    = (const int*)d_in[1];     // [2, E]: row = ei, col = ei + E
    const float* W1    = (const float*)d_in[2];
    const float* b1    = (const float*)d_in[3];
    const float* g1    = (const float*)d_in[4];
    const float* beta1 = (const float*)d_in[5];
    const float* rm1   = (const float*)d_in[6];
    const float* rv1   = (const float*)d_in[7];
    const float* W2    = (const float*)d_in[8];
    const float* b2    = (const float*)d_in[9];
    const float* g2    = (const float*)d_in[10];
    const float* beta2 = (const float*)d_in[11];
    const float* rm2   = (const float*)d_in[12];
    const float* rv2   = (const float*)d_in[13];
    float* out = (float*)d_out;

    // workspace layout (~12.5 MB)
    unsigned short* wt     = (unsigned short*)d_ws;             // NPAD*KPAD
    unsigned short* h1main = wt + (size_t)NPAD * KPAD;          // N*256
    unsigned short* h1t    = h1main + (size_t)N_NODES * MCOLS;  // N*16
    float* z    = (float*)(h1t + (size_t)N_NODES * TCOLS);
    float* dis  = z + N_NODES;
    int* counts = (int*)(dis + N_NODES);
    int* offs   = counts + N_NODES;
    int* cursor = offs + N_NODES + 1;
    int* esrc   = cursor + N_NODES;
    int* bsums  = esrc + N_EDGES;                               // NB_SCAN

    const int* row = ei;
    const int* col = ei + N_EDGES;

    hipMemsetAsync(counts, 0, N_NODES * sizeof(int), stream);

    int eb = (N_EDGES + 255) / 256;
    count_kernel<<<eb, 256, 0, stream>>>(col, counts);
    scan1_kernel<<<NB_SCAN, 256, 0, stream>>>(counts, offs, bsums, dis);
    scan3_kernel<<<NB_SCAN, 256, 0, stream>>>(bsums, offs, cursor);
    fill_kernel<<<eb, 256, 0, stream>>>(row, col, cursor, esrc);

    conv_w<<<(NPAD * KPAD + 255) / 256, 256, 0, stream>>>(W1, wt);

    int nwaves = (N_NODES / 32) * 9;                 // 5625
    gemm_mfma<<<(nwaves + 3) / 4, 256, 0, stream>>>(x, wt, h1main, h1t);

    agg1_kernel<<<2048, 256, 0, stream>>>(h1main, h1t, offs, esrc, dis,
                                          b1, g1, beta1, rm1, rv1, W2, z);
    agg2_kernel<<<(N_NODES + 255) / 256, 256, 0, stream>>>(z, offs, esrc, dis,
                                                           b2, g2, beta2, rm2, rv2, out);
}

// Round 10
// 124.449 us; speedup vs baseline: 1.0943x; 1.0202x over previous
//
#include <hip/hip_runtime.h>
#include <hip/hip_bf16.h>

#define N_NODES 20000
#define N_EDGES 300000
#define FDIM    268
#define KPAD    288   // K padded to 9*32 for mfma K-loop
#define NPAD    288   // N padded to 9*32
#define MCOLS   256   // main h1 row (bf16), 32 slots of 8
#define TCOLS   16    // tail h1 row (bf16), 2 slots (12 valid + 4 zero)
#define XSLOTS  (KPAD / 8)   // 36
#define EPS     1e-3f
#define NB_SCAN ((N_NODES + 255) / 256)   // 79

typedef __attribute__((ext_vector_type(8))) short short8;
typedef __attribute__((ext_vector_type(4))) float f32x4;
typedef __attribute__((ext_vector_type(8))) unsigned short ushort8;

__device__ inline short f2bf(float f) {
    __hip_bfloat16 b = __float2bfloat16(f);   // RNE
    return *reinterpret_cast<short*>(&b);
}
__device__ inline float bf2f(unsigned short u) {
    return __uint_as_float(((unsigned int)u) << 16);
}

// ---------------- CSR build ----------------

__global__ void count_kernel(const int* __restrict__ col, int* __restrict__ counts) {
    int e = blockIdx.x * blockDim.x + threadIdx.x;
    if (e < N_EDGES) atomicAdd(&counts[col[e]], 1);
}

// stage 1: per-block exclusive scan (256 elems/block) -> offs (no base), block sums; dis
__global__ __launch_bounds__(256) void scan1_kernel(const int* __restrict__ counts,
                                                    int* __restrict__ offs,
                                                    int* __restrict__ bsums,
                                                    float* __restrict__ dis) {
    int t = threadIdx.x;
    int i = blockIdx.x * 256 + t;
    int c = (i < N_NODES) ? counts[i] : 0;
    int lane = t & 63, w = t >> 6;
    int v = c;
#pragma unroll
    for (int off = 1; off < 64; off <<= 1) {
        int u = __shfl_up(v, off);
        if (lane >= off) v += u;
    }
    __shared__ int wsum[4];
    if (lane == 63) wsum[w] = v;
    __syncthreads();
    int wbase = 0;
#pragma unroll
    for (int k = 0; k < 4; ++k) if (k < w) wbase += wsum[k];
    int incl = v + wbase;
    if (i < N_NODES) {
        offs[i] = incl - c;                         // block-local exclusive
        dis[i]  = rsqrtf((float)(c + 1));           // +1 self-loop
    }
    if (t == 255) bsums[blockIdx.x] = incl;         // block total (padding adds 0)
}

// stage 2 (merged): each block computes its own base from bsums, adds, inits cursor
__global__ __launch_bounds__(256) void scan3_kernel(const int* __restrict__ bsums,
                                                    int* __restrict__ offs,
                                                    int* __restrict__ cursor) {
    __shared__ int red[256];
    int t = threadIdx.x;
    int b = blockIdx.x;
    red[t] = (t < NB_SCAN && t < b) ? bsums[t] : 0;
    __syncthreads();
#pragma unroll
    for (int st = 128; st > 0; st >>= 1) {
        if (t < st) red[t] += red[t + st];
        __syncthreads();
    }
    int base = red[0];
    int i = b * 256 + t;
    if (i < N_NODES) {
        int o = offs[i] + base;
        offs[i] = o;
        cursor[i] = o;
    }
    if (b == NB_SCAN - 1 && t == 0) offs[N_NODES] = base + bsums[b];
}

__global__ void fill_kernel(const int* __restrict__ row, const int* __restrict__ col,
                            int* __restrict__ cursor, int* __restrict__ esrc) {
    int e = blockIdx.x * blockDim.x + threadIdx.x;
    if (e < N_EDGES) {
        int c = col[e];
        int p = atomicAdd(&cursor[c], 1);
        esrc[p] = row[e];
    }
}

// ---------------- W1 -> W1^T bf16, zero-padded [NPAD][KPAD] ----------------
__global__ void conv_w(const float* __restrict__ W1, unsigned short* __restrict__ wt) {
    int idx = blockIdx.x * blockDim.x + threadIdx.x;
    if (idx >= NPAD * KPAD) return;
    int n = idx / KPAD, k = idx - n * KPAD;
    float v = (n < FDIM && k < FDIM) ? W1[(size_t)k * FDIM + n] : 0.f;
    wt[idx] = (unsigned short)f2bf(v);
}

// ---------------- x f32 [N][268] -> xb bf16 [N][288] zero-padded ----------------
// one thread per 8-col slot; rows are 16B-aligned (1072B), slots 0..32 fully valid.
__global__ __launch_bounds__(256) void conv_x(const float* __restrict__ x,
                                              unsigned short* __restrict__ xb) {
    int idx = blockIdx.x * blockDim.x + threadIdx.x;
    if (idx >= N_NODES * XSLOTS) return;
    int r = idx / XSLOTS, sl = idx - r * XSLOTS;
    int c0 = sl * 8;
    ushort8 o;
    if (c0 + 8 <= FDIM) {
        const float4* xr = reinterpret_cast<const float4*>(x + (size_t)r * FDIM + c0);
        float4 v0 = xr[0], v1 = xr[1];
        o[0] = (unsigned short)f2bf(v0.x); o[1] = (unsigned short)f2bf(v0.y);
        o[2] = (unsigned short)f2bf(v0.z); o[3] = (unsigned short)f2bf(v0.w);
        o[4] = (unsigned short)f2bf(v1.x); o[5] = (unsigned short)f2bf(v1.y);
        o[6] = (unsigned short)f2bf(v1.z); o[7] = (unsigned short)f2bf(v1.w);
    } else {
#pragma unroll
        for (int j = 0; j < 8; ++j) {
            int c = c0 + j;
            float v = (c < FDIM) ? x[(size_t)r * FDIM + c] : 0.f;
            o[j] = (unsigned short)f2bf(v);
        }
    }
    *reinterpret_cast<ushort8*>(xb + (size_t)r * KPAD + c0) = o;
}

// ---------------- GEMM: xb bf16 @ wt bf16 -> h1main [N][256] + h1t [N][16] ----------------
// wave computes 32x32 via 2x2 mfma_f32_16x16x32_bf16 frags; A and B both 16B vector loads.
__global__ __launch_bounds__(256) void gemm_mfma(const unsigned short* __restrict__ xb,
                                                 const unsigned short* __restrict__ wt,
                                                 unsigned short* __restrict__ h1main,
                                                 unsigned short* __restrict__ h1t) {
    int wid = blockIdx.x * 4 + (threadIdx.x >> 6);
    int m_idx = wid / 9;                  // n fastest: 9 n-waves share the A m-strip
    int n_idx = wid - m_idx * 9;
    if (m_idx >= N_NODES / 32) return;
    int lane = threadIdx.x & 63;
    int lrow = lane & 15;
    int lkg  = lane >> 4;                 // k-group 0..3
    int m0 = m_idx * 32, n0 = n_idx * 32;

    f32x4 acc[2][2];
#pragma unroll
    for (int a = 0; a < 2; ++a)
#pragma unroll
        for (int b = 0; b < 2; ++b) acc[a][b] = (f32x4){0.f, 0.f, 0.f, 0.f};

    const unsigned short* xr0 = xb + (size_t)(m0 + lrow) * KPAD;
    const unsigned short* xr1 = xb + (size_t)(m0 + 16 + lrow) * KPAD;
    const unsigned short* wr0 = wt + (size_t)(n0 + lrow) * KPAD;
    const unsigned short* wr1 = wt + (size_t)(n0 + 16 + lrow) * KPAD;

#pragma unroll
    for (int k0 = 0; k0 < KPAD; k0 += 32) {
        const int kb = k0 + lkg * 8;
        short8 a0 = *reinterpret_cast<const short8*>(xr0 + kb);
        short8 a1 = *reinterpret_cast<const short8*>(xr1 + kb);
        short8 b0 = *reinterpret_cast<const short8*>(wr0 + kb);
        short8 b1 = *reinterpret_cast<const short8*>(wr1 + kb);
        acc[0][0] = __builtin_amdgcn_mfma_f32_16x16x32_bf16(a0, b0, acc[0][0], 0, 0, 0);
        acc[0][1] = __builtin_amdgcn_mfma_f32_16x16x32_bf16(a0, b1, acc[0][1], 0, 0, 0);
        acc[1][0] = __builtin_amdgcn_mfma_f32_16x16x32_bf16(a1, b0, acc[1][0], 0, 0, 0);
        acc[1][1] = __builtin_amdgcn_mfma_f32_16x16x32_bf16(a1, b1, acc[1][1], 0, 0, 0);
    }

    // C/D layout: col = lane&15, row = (lane>>4)*4 + reg   [m89-verified]
#pragma unroll
    for (int mi = 0; mi < 2; ++mi)
#pragma unroll
        for (int ni = 0; ni < 2; ++ni) {
            int colg = n0 + ni * 16 + lrow;
#pragma unroll
            for (int r = 0; r < 4; ++r) {
                int rowg = m0 + mi * 16 + lkg * 4 + r;
                unsigned short hv = (unsigned short)f2bf(acc[mi][ni][r]);
                if (colg < MCOLS) {
                    h1main[(size_t)rowg * MCOLS + colg] = hv;
                } else if (colg < MCOLS + TCOLS) {
                    h1t[(size_t)rowg * TCOLS + (colg - MCOLS)] = hv;
                }
            }
        }
}

// ---------------- agg1: pull-aggregate + bias+relu+bn+relu + dot(W2) -> z ----------------
// grid-stride over nodes, one wave per node.
// Main (256 feats): half-wave (32 lanes x 16B) per row, 4 loads / 8 edges, zero-padded uniform loop.
// Tail (12 feats): all 64 lanes, lane l -> edge (l>>1), slot (l&1), from compact L2-resident h1t.
__global__ __launch_bounds__(256) void agg1_kernel(const unsigned short* __restrict__ h1main,
                                                   const unsigned short* __restrict__ h1t,
                                                   const int* __restrict__ offs,
                                                   const int* __restrict__ esrc,
                                                   const float* __restrict__ dis,
                                                   const float* __restrict__ b1,
                                                   const float* __restrict__ g1,
                                                   const float* __restrict__ beta1,
                                                   const float* __restrict__ rm1,
                                                   const float* __restrict__ rv1,
                                                   const float* __restrict__ W2,
                                                   float* __restrict__ z) {
    const int lane = threadIdx.x & 63;
    const int h  = lane >> 5;       // half 0/1
    const int sl = lane & 31;       // slot 0..31 (features sl*8..sl*8+7)
    const int wave0 = blockIdx.x * 4 + (threadIdx.x >> 6);
    const int wstride = gridDim.x * 4;
    const ushort8* mbase = reinterpret_cast<const ushort8*>(h1main);
    const ushort8* tbase = reinterpret_cast<const ushort8*>(h1t);

    for (int i = wave0; i < N_NODES; i += wstride) {
        float a[8]  = {0.f, 0.f, 0.f, 0.f, 0.f, 0.f, 0.f, 0.f};
        float tb[8] = {0.f, 0.f, 0.f, 0.f, 0.f, 0.f, 0.f, 0.f};

        const int s = offs[i], e = offs[i + 1];
        const int deg = e - s;
        const float di = dis[i];

        // self-loop main (h==0 half carries weight di, h==1 adds exact 0)
        {
            const float ws = (h == 0) ? di : 0.f;
            ushort8 v = mbase[(size_t)i * 32 + sl];
#pragma unroll
            for (int j = 0; j < 8; ++j) a[j] += ws * bf2f(v[j]);
        }
        // self-loop tail (lanes 0,1 -> slots 0,1)
        if (lane < 2) {
            ushort8 v = tbase[(size_t)i * 2 + lane];
#pragma unroll
            for (int j = 0; j < 8; ++j) tb[j] += di * bf2f(v[j]);
        }

        for (int c0 = 0; c0 < deg; c0 += 64) {
            int cnt = deg - c0; if (cnt > 64) cnt = 64;
            int   lsrc = 0;
            float lw   = 0.f;
            if (lane < cnt) {
                lsrc = esrc[s + c0 + lane];    // coalesced
                lw   = dis[lsrc];
            }
            // ---- main: 8 edges/iter (4 per half), pads contribute exact 0 ----
            const int niter = (cnt + 7) >> 3;
            for (int k = 0; k < niter; ++k) {
                int p = h + k * 8;
                int   s0 = __shfl(lsrc, p),     s1 = __shfl(lsrc, p + 2);
                int   s2 = __shfl(lsrc, p + 4), s3 = __shfl(lsrc, p + 6);
                float w0 = __shfl(lw, p),       w1 = __shfl(lw, p + 2);
                float w2 = __shfl(lw, p + 4),   w3 = __shfl(lw, p + 6);
                ushort8 v0 = mbase[(size_t)s0 * 32 + sl];
                ushort8 v1 = mbase[(size_t)s1 * 32 + sl];
                ushort8 v2 = mbase[(size_t)s2 * 32 + sl];
                ushort8 v3 = mbase[(size_t)s3 * 32 + sl];
#pragma unroll
                for (int j = 0; j < 8; ++j)
                    a[j] += w0 * bf2f(v0[j]) + w1 * bf2f(v1[j]) + w2 * bf2f(v2[j]) + w3 * bf2f(v3[j]);
            }
            // ---- tail: 32 edges/iter, lane l -> edge (l>>1), slot (l&1) ----
            const int tniter = (cnt + 31) >> 5;
            for (int k = 0; k < tniter; ++k) {
                int ei = k * 32 + (lane >> 1);
                int   ts = __shfl(lsrc, ei);
                float tw = __shfl(lw, ei);
                ushort8 v = tbase[(size_t)ts * 2 + (lane & 1)];
#pragma unroll
                for (int j = 0; j < 8; ++j) tb[j] += tw * bf2f(v[j]);
            }
        }

        // merge halves (main)
#pragma unroll
        for (int j = 0; j < 8; ++j) a[j] += __shfl_xor(a[j], 32);
        // reduce tail across lanes sharing (lane&1)
#pragma unroll
        for (int j = 0; j < 8; ++j) {
            tb[j] += __shfl_xor(tb[j], 2);
            tb[j] += __shfl_xor(tb[j], 4);
            tb[j] += __shfl_xor(tb[j], 8);
            tb[j] += __shfl_xor(tb[j], 16);
            tb[j] += __shfl_xor(tb[j], 32);
        }

        float zp = 0.f;
        if (h == 0) {
            int f0 = sl * 8;
#pragma unroll
            for (int j = 0; j < 8; ++j) {
                int f = f0 + j;
                float v = fmaxf(di * a[j] + b1[f], 0.f);
                v = fmaxf((v - rm1[f]) * rsqrtf(rv1[f] + EPS) * g1[f] + beta1[f], 0.f);
                zp += v * W2[f];
            }
            if (sl < 2) {
                int ft0 = 256 + sl * 8;
#pragma unroll
                for (int j = 0; j < 8; ++j) {
                    int f = ft0 + j;
                    if (f < FDIM) {
                        float v = fmaxf(di * tb[j] + b1[f], 0.f);
                        v = fmaxf((v - rm1[f]) * rsqrtf(rv1[f] + EPS) * g1[f] + beta1[f], 0.f);
                        zp += v * W2[f];
                    }
                }
            }
        }
#pragma unroll
        for (int off = 32; off > 0; off >>= 1) zp += __shfl_xor(zp, off);
        if (lane == 0) z[i] = zp;
    }
}

// ---------------- agg2: pull-aggregate z + bias + bn + relu + sigmoid -> out ----------------
__global__ void agg2_kernel(const float* __restrict__ z,
                            const int* __restrict__ offs,
                            const int* __restrict__ esrc,
                            const float* __restrict__ dis,
                            const float* __restrict__ b2,
                            const float* __restrict__ g2,
                            const float* __restrict__ beta2,
                            const float* __restrict__ rm2,
                            const float* __restrict__ rv2,
                            float* __restrict__ out) {
    int i = blockIdx.x * blockDim.x + threadIdx.x;
    if (i >= N_NODES) return;
    int s = offs[i], e = offs[i + 1];
    float acc = 0.f;
    int p = s;
    for (; p + 3 < e; p += 4) {   // 4 gathers in flight
        int s0 = esrc[p], s1 = esrc[p + 1], s2 = esrc[p + 2], s3 = esrc[p + 3];
        acc += dis[s0] * z[s0] + dis[s1] * z[s1] + dis[s2] * z[s2] + dis[s3] * z[s3];
    }
    for (; p < e; ++p) {
        int s0 = esrc[p];
        acc += dis[s0] * z[s0];
    }
    float di = dis[i];
    acc += di * z[i];                 // self loop
    float pre = di * acc + b2[0];
    float v = (pre - rm2[0]) * rsqrtf(rv2[0] + EPS) * g2[0] + beta2[0];
    v = fmaxf(v, 0.f);
    out[i] = 1.f / (1.f + expf(-v));
}

// ---------------- launcher ----------------
extern "C" void kernel_launch(void* const* d_in, const int* in_sizes, int n_in,
                              void* d_out, int out_size, void* d_ws, size_t ws_size,
                              hipStream_t stream) {
    const float* x     = (const float*)d_in[0];
    const int*   ei    = (const int*)d_in[1];     // [2, E]: row = ei, col = ei + E
    const float* W1    = (const float*)d_in[2];
    const float* b1    = (const float*)d_in[3];
    const float* g1    = (const float*)d_in[4];
    const float* beta1 = (const float*)d_in[5];
    const float* rm1   = (const float*)d_in[6];
    const float* rv1   = (const float*)d_in[7];
    const float* W2    = (const float*)d_in[8];
    const float* b2    = (const float*)d_in[9];
    const float* g2    = (const float*)d_in[10];
    const float* beta2 = (const float*)d_in[11];
    const float* rm2   = (const float*)d_in[12];
    const float* rv2   = (const float*)d_in[13];
    float* out = (float*)d_out;

    // workspace layout (~24 MB)
    unsigned short* wt     = (unsigned short*)d_ws;             // NPAD*KPAD
    unsigned short* xb     = wt + (size_t)NPAD * KPAD;          // N*KPAD
    unsigned short* h1main = xb + (size_t)N_NODES * KPAD;       // N*256
    unsigned short* h1t    = h1main + (size_t)N_NODES * MCOLS;  // N*16
    float* z    = (float*)(h1t + (size_t)N_NODES * TCOLS);
    float* dis  = z + N_NODES;
    int* counts = (int*)(dis + N_NODES);
    int* offs   = counts + N_NODES;
    int* cursor = offs + N_NODES + 1;
    int* esrc   = cursor + N_NODES;
    int* bsums  = esrc + N_EDGES;                               // NB_SCAN

    const int* row = ei;
    const int* col = ei + N_EDGES;

    hipMemsetAsync(counts, 0, N_NODES * sizeof(int), stream);

    int eb = (N_EDGES + 255) / 256;
    count_kernel<<<eb, 256, 0, stream>>>(col, counts);
    scan1_kernel<<<NB_SCAN, 256, 0, stream>>>(counts, offs, bsums, dis);
    scan3_kernel<<<NB_SCAN, 256, 0, stream>>>(bsums, offs, cursor);
    fill_kernel<<<eb, 256, 0, stream>>>(row, col, cursor, esrc);

    conv_w<<<(NPAD * KPAD + 255) / 256, 256, 0, stream>>>(W1, wt);
    conv_x<<<(N_NODES * XSLOTS + 255) / 256, 256, 0, stream>>>(x, xb);

    int nwaves = (N_NODES / 32) * 9;                 // 5625
    gemm_mfma<<<(nwaves + 3) / 4, 256, 0, stream>>>(xb, wt, h1main, h1t);

    agg1_kernel<<<2048, 256, 0, stream>>>(h1main, h1t, offs, esrc, dis,
                                          b1, g1, beta1, rm1, rv1, W2, z);
    agg2_kernel<<<(N_NODES + 255) / 256, 256, 0, stream>>>(z, offs, esrc, dis,
                                                           b2, g2, beta2, rm2, rv2, out);
}

// Round 11
// 115.768 us; speedup vs baseline: 1.1763x; 1.0750x over previous
//
#include <hip/hip_runtime.h>
#include <hip/hip_bf16.h>

#define N_NODES 20000
#define N_EDGES 300000
#define FDIM    268
#define KPAD    288   // K padded to 9*32 for mfma K-loop
#define NPAD    288   // N padded to 9*32
#define MCOLS   256   // main h1 row (bf16), 32 slots of 8
#define TCOLS   16    // tail h1 row (bf16), 2 slots (12 valid + 4 zero)
#define ASTRIDE 296   // LDS A row stride in ushort (592B: 16B-aligned, 2-way bank worst case)
#define EPS     1e-3f
#define NB_SCAN ((N_NODES + 255) / 256)   // 79

typedef __attribute__((ext_vector_type(8))) short short8;
typedef __attribute__((ext_vector_type(4))) float f32x4;
typedef __attribute__((ext_vector_type(8))) unsigned short ushort8;
typedef __attribute__((ext_vector_type(4))) unsigned short ushort4_t;

__device__ inline unsigned short f2bf(float f) {
    __hip_bfloat16 b = __float2bfloat16(f);   // RNE
    return *reinterpret_cast<unsigned short*>(&b);
}
__device__ inline float bf2f(unsigned short u) {
    return __uint_as_float(((unsigned int)u) << 16);
}

// ---------------- CSR build ----------------

__global__ void zero_kernel(int* __restrict__ counts) {
    int i = blockIdx.x * blockDim.x + threadIdx.x;
    if (i < N_NODES) counts[i] = 0;
}

__global__ void count_kernel(const int* __restrict__ col, int* __restrict__ counts) {
    int e = blockIdx.x * blockDim.x + threadIdx.x;
    if (e < N_EDGES) atomicAdd(&counts[col[e]], 1);
}

// stage 1: per-block exclusive scan (256 elems/block) -> offs (no base), block sums; dis
__global__ __launch_bounds__(256) void scan1_kernel(const int* __restrict__ counts,
                                                    int* __restrict__ offs,
                                                    int* __restrict__ bsums,
                                                    float* __restrict__ dis) {
    int t = threadIdx.x;
    int i = blockIdx.x * 256 + t;
    int c = (i < N_NODES) ? counts[i] : 0;
    int lane = t & 63, w = t >> 6;
    int v = c;
#pragma unroll
    for (int off = 1; off < 64; off <<= 1) {
        int u = __shfl_up(v, off);
        if (lane >= off) v += u;
    }
    __shared__ int wsum[4];
    if (lane == 63) wsum[w] = v;
    __syncthreads();
    int wbase = 0;
#pragma unroll
    for (int k = 0; k < 4; ++k) if (k < w) wbase += wsum[k];
    int incl = v + wbase;
    if (i < N_NODES) {
        offs[i] = incl - c;                         // block-local exclusive
        dis[i]  = rsqrtf((float)(c + 1));           // +1 self-loop
    }
    if (t == 255) bsums[blockIdx.x] = incl;         // block total (padding adds 0)
}

// stage 2 (merged): each block computes its own base from bsums, adds, inits cursor
__global__ __launch_bounds__(256) void scan3_kernel(const int* __restrict__ bsums,
                                                    int* __restrict__ offs,
                                                    int* __restrict__ cursor) {
    __shared__ int red[256];
    int t = threadIdx.x;
    int b = blockIdx.x;
    red[t] = (t < NB_SCAN && t < b) ? bsums[t] : 0;
    __syncthreads();
#pragma unroll
    for (int st = 128; st > 0; st >>= 1) {
        if (t < st) red[t] += red[t + st];
        __syncthreads();
    }
    int base = red[0];
    int i = b * 256 + t;
    if (i < N_NODES) {
        int o = offs[i] + base;
        offs[i] = o;
        cursor[i] = o;
    }
    if (b == NB_SCAN - 1 && t == 0) offs[N_NODES] = base + bsums[b];
}

__global__ void fill_kernel(const int* __restrict__ row, const int* __restrict__ col,
                            int* __restrict__ cursor, int* __restrict__ esrc) {
    int e = blockIdx.x * blockDim.x + threadIdx.x;
    if (e < N_EDGES) {
        int c = col[e];
        int p = atomicAdd(&cursor[c], 1);
        esrc[p] = row[e];
    }
}

// ---------------- W1 -> W1^T bf16, zero-padded [NPAD][KPAD] ----------------
__global__ void conv_w(const float* __restrict__ W1, unsigned short* __restrict__ wt) {
    int idx = blockIdx.x * blockDim.x + threadIdx.x;
    if (idx >= NPAD * KPAD) return;
    int n = idx / KPAD, k = idx - n * KPAD;
    float v = (n < FDIM && k < FDIM) ? W1[(size_t)k * FDIM + n] : 0.f;
    wt[idx] = f2bf(v);
}

// ---------------- GEMM: bf16(x) @ wt -> h1main [N][256] + h1t [N][16] ----------------
// one block per 32-row m-strip; A staged+converted f32->bf16 into LDS once;
// 4 waves sweep the 9 n-tiles (B rows L2-resident).
__global__ __launch_bounds__(256) void gemm_mfma(const float* __restrict__ x,
                                                 const unsigned short* __restrict__ wt,
                                                 unsigned short* __restrict__ h1main,
                                                 unsigned short* __restrict__ h1t) {
    __shared__ unsigned short As[32 * ASTRIDE];   // 18,944 B
    const int tid = threadIdx.x;
    const int m0 = blockIdx.x * 32;

    // stage: 32 rows x 72 slots of 4 cols (268 = 67 full float4 slots; 67..71 -> zero pad)
    for (int c = tid; c < 32 * 72; c += 256) {
        int r = c / 72, s = c - r * 72;
        ushort4_t o;
        if (s < 67) {
            float4 v = *reinterpret_cast<const float4*>(x + (size_t)(m0 + r) * FDIM + s * 4);
            o[0] = f2bf(v.x); o[1] = f2bf(v.y); o[2] = f2bf(v.z); o[3] = f2bf(v.w);
        } else {
            o[0] = 0; o[1] = 0; o[2] = 0; o[3] = 0;
        }
        *reinterpret_cast<ushort4_t*>(&As[r * ASTRIDE + s * 4]) = o;
    }
    __syncthreads();

    const int lane = tid & 63;
    const int w    = tid >> 6;
    const int lrow = lane & 15;
    const int lkg  = lane >> 4;           // k-group 0..3
    const unsigned short* a_r0 = &As[lrow * ASTRIDE];
    const unsigned short* a_r1 = &As[(lrow + 16) * ASTRIDE];

    for (int nt = w; nt < 9; nt += 4) {
        const int n0 = nt * 32;
        f32x4 acc[2][2];
#pragma unroll
        for (int a = 0; a < 2; ++a)
#pragma unroll
            for (int b = 0; b < 2; ++b) acc[a][b] = (f32x4){0.f, 0.f, 0.f, 0.f};

        const unsigned short* wr0 = wt + (size_t)(n0 + lrow) * KPAD;
        const unsigned short* wr1 = wt + (size_t)(n0 + 16 + lrow) * KPAD;

#pragma unroll
        for (int k0 = 0; k0 < KPAD; k0 += 32) {
            const int kb = k0 + lkg * 8;
            short8 a0 = *reinterpret_cast<const short8*>(a_r0 + kb);
            short8 a1 = *reinterpret_cast<const short8*>(a_r1 + kb);
            short8 b0 = *reinterpret_cast<const short8*>(wr0 + kb);
            short8 b1 = *reinterpret_cast<const short8*>(wr1 + kb);
            acc[0][0] = __builtin_amdgcn_mfma_f32_16x16x32_bf16(a0, b0, acc[0][0], 0, 0, 0);
            acc[0][1] = __builtin_amdgcn_mfma_f32_16x16x32_bf16(a0, b1, acc[0][1], 0, 0, 0);
            acc[1][0] = __builtin_amdgcn_mfma_f32_16x16x32_bf16(a1, b0, acc[1][0], 0, 0, 0);
            acc[1][1] = __builtin_amdgcn_mfma_f32_16x16x32_bf16(a1, b1, acc[1][1], 0, 0, 0);
        }

        // C/D layout: col = lane&15, row = (lane>>4)*4 + reg   [m89-verified]
#pragma unroll
        for (int mi = 0; mi < 2; ++mi)
#pragma unroll
            for (int ni = 0; ni < 2; ++ni) {
                int colg = n0 + ni * 16 + lrow;
#pragma unroll
                for (int r = 0; r < 4; ++r) {
                    int rowg = m0 + mi * 16 + lkg * 4 + r;
                    unsigned short hv = f2bf(acc[mi][ni][r]);
                    if (colg < MCOLS) {
                        h1main[(size_t)rowg * MCOLS + colg] = hv;
                    } else if (colg < MCOLS + TCOLS) {
                        h1t[(size_t)rowg * TCOLS + (colg - MCOLS)] = hv;
                    }
                }
            }
    }
}

// ---------------- agg1: pull-aggregate + bias+relu+bn+relu + dot(W2) -> z ----------------
// grid-stride over nodes, one wave per node.
// Main (256 feats): half-wave (32 lanes x 16B) per row, 4 loads / 8 edges, zero-padded uniform loop.
// Tail (12 feats): all 64 lanes, lane l -> edge (l>>1), slot (l&1), from compact L2-resident h1t.
__global__ __launch_bounds__(256) void agg1_kernel(const unsigned short* __restrict__ h1main,
                                                   const unsigned short* __restrict__ h1t,
                                                   const int* __restrict__ offs,
                                                   const int* __restrict__ esrc,
                                                   const float* __restrict__ dis,
                                                   const float* __restrict__ b1,
                                                   const float* __restrict__ g1,
                                                   const float* __restrict__ beta1,
                                                   const float* __restrict__ rm1,
                                                   const float* __restrict__ rv1,
                                                   const float* __restrict__ W2,
                                                   float* __restrict__ z) {
    const int lane = threadIdx.x & 63;
    const int h  = lane >> 5;       // half 0/1
    const int sl = lane & 31;       // slot 0..31 (features sl*8..sl*8+7)
    const int wave0 = blockIdx.x * 4 + (threadIdx.x >> 6);
    const int wstride = gridDim.x * 4;
    const ushort8* mbase = reinterpret_cast<const ushort8*>(h1main);
    const ushort8* tbase = reinterpret_cast<const ushort8*>(h1t);

    for (int i = wave0; i < N_NODES; i += wstride) {
        float a[8]  = {0.f, 0.f, 0.f, 0.f, 0.f, 0.f, 0.f, 0.f};
        float tb[8] = {0.f, 0.f, 0.f, 0.f, 0.f, 0.f, 0.f, 0.f};

        const int s = offs[i], e = offs[i + 1];
        const int deg = e - s;
        const float di = dis[i];

        // self-loop main (h==0 half carries weight di, h==1 adds exact 0)
        {
            const float ws = (h == 0) ? di : 0.f;
            ushort8 v = mbase[(size_t)i * 32 + sl];
#pragma unroll
            for (int j = 0; j < 8; ++j) a[j] += ws * bf2f(v[j]);
        }
        // self-loop tail (lanes 0,1 -> slots 0,1)
        if (lane < 2) {
            ushort8 v = tbase[(size_t)i * 2 + lane];
#pragma unroll
            for (int j = 0; j < 8; ++j) tb[j] += di * bf2f(v[j]);
        }

        for (int c0 = 0; c0 < deg; c0 += 64) {
            int cnt = deg - c0; if (cnt > 64) cnt = 64;
            int   lsrc = 0;
            float lw   = 0.f;
            if (lane < cnt) {
                lsrc = esrc[s + c0 + lane];    // coalesced
                lw   = dis[lsrc];
            }
            // ---- main: 8 edges/iter (4 per half), pads contribute exact 0 ----
            const int niter = (cnt + 7) >> 3;
            for (int k = 0; k < niter; ++k) {
                int p = h + k * 8;
                int   s0 = __shfl(lsrc, p),     s1 = __shfl(lsrc, p + 2);
                int   s2 = __shfl(lsrc, p + 4), s3 = __shfl(lsrc, p + 6);
                float w0 = __shfl(lw, p),       w1 = __shfl(lw, p + 2);
                float w2 = __shfl(lw, p + 4),   w3 = __shfl(lw, p + 6);
                ushort8 v0 = mbase[(size_t)s0 * 32 + sl];
                ushort8 v1 = mbase[(size_t)s1 * 32 + sl];
                ushort8 v2 = mbase[(size_t)s2 * 32 + sl];
                ushort8 v3 = mbase[(size_t)s3 * 32 + sl];
#pragma unroll
                for (int j = 0; j < 8; ++j)
                    a[j] += w0 * bf2f(v0[j]) + w1 * bf2f(v1[j]) + w2 * bf2f(v2[j]) + w3 * bf2f(v3[j]);
            }
            // ---- tail: 32 edges/iter, lane l -> edge (l>>1), slot (l&1) ----
            const int tniter = (cnt + 31) >> 5;
            for (int k = 0; k < tniter; ++k) {
                int ei = k * 32 + (lane >> 1);
                int   ts = __shfl(lsrc, ei);
                float tw = __shfl(lw, ei);
                ushort8 v = tbase[(size_t)ts * 2 + (lane & 1)];
#pragma unroll
                for (int j = 0; j < 8; ++j) tb[j] += tw * bf2f(v[j]);
            }
        }

        // merge halves (main)
#pragma unroll
        for (int j = 0; j < 8; ++j) a[j] += __shfl_xor(a[j], 32);
        // reduce tail across lanes sharing (lane&1)
#pragma unroll
        for (int j = 0; j < 8; ++j) {
            tb[j] += __shfl_xor(tb[j], 2);
            tb[j] += __shfl_xor(tb[j], 4);
            tb[j] += __shfl_xor(tb[j], 8);
            tb[j] += __shfl_xor(tb[j], 16);
            tb[j] += __shfl_xor(tb[j], 32);
        }

        float zp = 0.f;
        if (h == 0) {
            int f0 = sl * 8;
#pragma unroll
            for (int j = 0; j < 8; ++j) {
                int f = f0 + j;
                float v = fmaxf(di * a[j] + b1[f], 0.f);
                v = fmaxf((v - rm1[f]) * rsqrtf(rv1[f] + EPS) * g1[f] + beta1[f], 0.f);
                zp += v * W2[f];
            }
            if (sl < 2) {
                int ft0 = 256 + sl * 8;
#pragma unroll
                for (int j = 0; j < 8; ++j) {
                    int f = ft0 + j;
                    if (f < FDIM) {
                        float v = fmaxf(di * tb[j] + b1[f], 0.f);
                        v = fmaxf((v - rm1[f]) * rsqrtf(rv1[f] + EPS) * g1[f] + beta1[f], 0.f);
                        zp += v * W2[f];
                    }
                }
            }
        }
#pragma unroll
        for (int off = 32; off > 0; off >>= 1) zp += __shfl_xor(zp, off);
        if (lane == 0) z[i] = zp;
    }
}

// ---------------- agg2: pull-aggregate z + bias + bn + relu + sigmoid -> out ----------------
__global__ void agg2_kernel(const float* __restrict__ z,
                            const int* __restrict__ offs,
                            const int* __restrict__ esrc,
                            const float* __restrict__ dis,
                            const float* __restrict__ b2,
                            const float* __restrict__ g2,
                            const float* __restrict__ beta2,
                            const float* __restrict__ rm2,
                            const float* __restrict__ rv2,
                            float* __restrict__ out) {
    int i = blockIdx.x * blockDim.x + threadIdx.x;
    if (i >= N_NODES) return;
    int s = offs[i], e = offs[i + 1];
    float acc = 0.f;
    int p = s;
    for (; p + 3 < e; p += 4) {   // 4 gathers in flight
        int s0 = esrc[p], s1 = esrc[p + 1], s2 = esrc[p + 2], s3 = esrc[p + 3];
        acc += dis[s0] * z[s0] + dis[s1] * z[s1] + dis[s2] * z[s2] + dis[s3] * z[s3];
    }
    for (; p < e; ++p) {
        int s0 = esrc[p];
        acc += dis[s0] * z[s0];
    }
    float di = dis[i];
    acc += di * z[i];                 // self loop
    float pre = di * acc + b2[0];
    float v = (pre - rm2[0]) * rsqrtf(rv2[0] + EPS) * g2[0] + beta2[0];
    v = fmaxf(v, 0.f);
    out[i] = 1.f / (1.f + expf(-v));
}

// ---------------- launcher ----------------
extern "C" void kernel_launch(void* const* d_in, const int* in_sizes, int n_in,
                              void* d_out, int out_size, void* d_ws, size_t ws_size,
                              hipStream_t stream) {
    const float* x     = (const float*)d_in[0];
    const int*   ei    = (const int*)d_in[1];     // [2, E]: row = ei, col = ei + E
    const float* W1    = (const float*)d_in[2];
    const float* b1    = (const float*)d_in[3];
    const float* g1    = (const float*)d_in[4];
    const float* beta1 = (const float*)d_in[5];
    const float* rm1   = (const float*)d_in[6];
    const float* rv1   = (const float*)d_in[7];
    const float* W2    = (const float*)d_in[8];
    const float* b2    = (const float*)d_in[9];
    const float* g2    = (const float*)d_in[10];
    const float* beta2 = (const float*)d_in[11];
    const float* rm2   = (const float*)d_in[12];
    const float* rv2   = (const float*)d_in[13];
    float* out = (float*)d_out;

    // workspace layout (~13 MB)
    unsigned short* wt     = (unsigned short*)d_ws;             // NPAD*KPAD
    unsigned short* h1main = wt + (size_t)NPAD * KPAD;          // N*256
    unsigned short* h1t    = h1main + (size_t)N_NODES * MCOLS;  // N*16
    float* z    = (float*)(h1t + (size_t)N_NODES * TCOLS);
    float* dis  = z + N_NODES;
    int* counts = (int*)(dis + N_NODES);
    int* offs   = counts + N_NODES;
    int* cursor = offs + N_NODES + 1;
    int* esrc   = cursor + N_NODES;
    int* bsums  = esrc + N_EDGES;                               // NB_SCAN

    const int* row = ei;
    const int* col = ei + N_EDGES;

    int eb = (N_EDGES + 255) / 256;
    zero_kernel<<<NB_SCAN, 256, 0, stream>>>(counts);
    count_kernel<<<eb, 256, 0, stream>>>(col, counts);
    scan1_kernel<<<NB_SCAN, 256, 0, stream>>>(counts, offs, bsums, dis);
    scan3_kernel<<<NB_SCAN, 256, 0, stream>>>(bsums, offs, cursor);
    fill_kernel<<<eb, 256, 0, stream>>>(row, col, cursor, esrc);

    conv_w<<<(NPAD * KPAD + 255) / 256, 256, 0, stream>>>(W1, wt);

    gemm_mfma<<<N_NODES / 32, 256, 0, stream>>>(x, wt, h1main, h1t);

    agg1_kernel<<<2048, 256, 0, stream>>>(h1main, h1t, offs, esrc, dis,
                                          b1, g1, beta1, rm1, rv1, W2, z);
    agg2_kernel<<<(N_NODES + 255) / 256, 256, 0, stream>>>(z, offs, esrc, dis,
                                                           b2, g2, beta2, rm2, rv2, out);
}

// Round 12
// 110.091 us; speedup vs baseline: 1.2370x; 1.0516x over previous
//
#include <hip/hip_runtime.h>
#include <hip/hip_bf16.h>

#define N_NODES 20000
#define N_EDGES 300000
#define FDIM    268
#define KPAD    288   // K padded to 9*32 for mfma K-loop
#define NPAD    288   // N padded to 9*32
#define MCOLS   256   // main h1 row (bf16), 32 slots of 8
#define TCOLS   16    // tail h1 row (bf16), 2 slots (12 valid + 4 zero)
#define ASTRIDE 296   // LDS A row stride in ushort (592B: 16B-aligned, 2-way bank worst case)
#define EPS     1e-3f
#define NB_SCAN ((N_NODES + 255) / 256)   // 79
#define NB_CONVW ((NPAD * KPAD + 255) / 256)  // 324

typedef __attribute__((ext_vector_type(8))) short short8;
typedef __attribute__((ext_vector_type(4))) float f32x4;
typedef __attribute__((ext_vector_type(8))) unsigned short ushort8;
typedef __attribute__((ext_vector_type(4))) unsigned short ushort4_t;

__device__ inline unsigned short f2bf(float f) {
    __hip_bfloat16 b = __float2bfloat16(f);   // RNE
    return *reinterpret_cast<unsigned short*>(&b);
}
__device__ inline float bf2f(unsigned short u) {
    return __uint_as_float(((unsigned int)u) << 16);
}

// ---------------- prep: zero counts (blocks >= NB_CONVW) + W1 -> W1^T bf16 (blocks < NB_CONVW) ----------------
__global__ void prep_kernel(const float* __restrict__ W1, unsigned short* __restrict__ wt,
                            int* __restrict__ counts) {
    int b = blockIdx.x;
    if (b < NB_CONVW) {
        int idx = b * 256 + threadIdx.x;
        if (idx >= NPAD * KPAD) return;
        int n = idx / KPAD, k = idx - n * KPAD;
        float v = (n < FDIM && k < FDIM) ? W1[(size_t)k * FDIM + n] : 0.f;
        wt[idx] = f2bf(v);
    } else {
        int i = (b - NB_CONVW) * 256 + threadIdx.x;
        if (i < N_NODES) counts[i] = 0;
    }
}

__global__ void count_kernel(const int* __restrict__ col, int* __restrict__ counts) {
    int e = blockIdx.x * blockDim.x + threadIdx.x;
    if (e < N_EDGES) atomicAdd(&counts[col[e]], 1);
}

// stage 1: per-block exclusive scan (256 elems/block) -> offs (no base), block sums; dis
__global__ __launch_bounds__(256) void scan1_kernel(const int* __restrict__ counts,
                                                    int* __restrict__ offs,
                                                    int* __restrict__ bsums,
                                                    float* __restrict__ dis) {
    int t = threadIdx.x;
    int i = blockIdx.x * 256 + t;
    int c = (i < N_NODES) ? counts[i] : 0;
    int lane = t & 63, w = t >> 6;
    int v = c;
#pragma unroll
    for (int off = 1; off < 64; off <<= 1) {
        int u = __shfl_up(v, off);
        if (lane >= off) v += u;
    }
    __shared__ int wsum[4];
    if (lane == 63) wsum[w] = v;
    __syncthreads();
    int wbase = 0;
#pragma unroll
    for (int k = 0; k < 4; ++k) if (k < w) wbase += wsum[k];
    int incl = v + wbase;
    if (i < N_NODES) {
        offs[i] = incl - c;                         // block-local exclusive
        dis[i]  = rsqrtf((float)(c + 1));           // +1 self-loop
    }
    if (t == 255) bsums[blockIdx.x] = incl;         // block total (padding adds 0)
}

// stage 2 (merged): each block computes its own base from bsums, adds, inits cursor
__global__ __launch_bounds__(256) void scan3_kernel(const int* __restrict__ bsums,
                                                    int* __restrict__ offs,
                                                    int* __restrict__ cursor) {
    __shared__ int red[256];
    int t = threadIdx.x;
    int b = blockIdx.x;
    red[t] = (t < NB_SCAN && t < b) ? bsums[t] : 0;
    __syncthreads();
#pragma unroll
    for (int st = 128; st > 0; st >>= 1) {
        if (t < st) red[t] += red[t + st];
        __syncthreads();
    }
    int base = red[0];
    int i = b * 256 + t;
    if (i < N_NODES) {
        int o = offs[i] + base;
        offs[i] = o;
        cursor[i] = o;
    }
    if (b == NB_SCAN - 1 && t == 0) offs[N_NODES] = base + bsums[b];
}

__global__ void fill_kernel(const int* __restrict__ row, const int* __restrict__ col,
                            int* __restrict__ cursor, int* __restrict__ esrc) {
    int e = blockIdx.x * blockDim.x + threadIdx.x;
    if (e < N_EDGES) {
        int c = col[e];
        int p = atomicAdd(&cursor[c], 1);
        esrc[p] = row[e];
    }
}

// ---------------- GEMM: bf16(x) @ wt -> h1main [N][256] + h1t [N][16] ----------------
// one block (512 thr = 8 waves) per 32-row m-strip; A staged f32->bf16 into LDS once;
// wave w owns n-tile w (wave 0 also does tile 8); 18 B-loads per tile fully unrolled.
__global__ __launch_bounds__(512) void gemm_mfma(const float* __restrict__ x,
                                                 const unsigned short* __restrict__ wt,
                                                 unsigned short* __restrict__ h1main,
                                                 unsigned short* __restrict__ h1t) {
    __shared__ unsigned short As[32 * ASTRIDE];   // 18,944 B
    const int tid = threadIdx.x;
    const int m0 = blockIdx.x * 32;

    // stage: 32 rows x 72 slots of 4 cols (268 = 67 full float4 slots; 67..71 -> zero pad)
    for (int c = tid; c < 32 * 72; c += 512) {
        int r = c / 72, s = c - r * 72;
        ushort4_t o;
        if (s < 67) {
            float4 v = *reinterpret_cast<const float4*>(x + (size_t)(m0 + r) * FDIM + s * 4);
            o[0] = f2bf(v.x); o[1] = f2bf(v.y); o[2] = f2bf(v.z); o[3] = f2bf(v.w);
        } else {
            o[0] = 0; o[1] = 0; o[2] = 0; o[3] = 0;
        }
        *reinterpret_cast<ushort4_t*>(&As[r * ASTRIDE + s * 4]) = o;
    }
    __syncthreads();

    const int lane = tid & 63;
    const int w    = tid >> 6;            // wave 0..7
    const int lrow = lane & 15;
    const int lkg  = lane >> 4;           // k-group 0..3
    const unsigned short* a_r0 = &As[lrow * ASTRIDE];
    const unsigned short* a_r1 = &As[(lrow + 16) * ASTRIDE];

    for (int nt = w; nt < 9; nt += 8) {   // wave 0: tiles {0,8}; waves 1..7: one tile
        const int n0 = nt * 32;
        f32x4 acc[2][2];
#pragma unroll
        for (int a = 0; a < 2; ++a)
#pragma unroll
            for (int b = 0; b < 2; ++b) acc[a][b] = (f32x4){0.f, 0.f, 0.f, 0.f};

        const unsigned short* wr0 = wt + (size_t)(n0 + lrow) * KPAD;
        const unsigned short* wr1 = wt + (size_t)(n0 + 16 + lrow) * KPAD;

#pragma unroll
        for (int k0 = 0; k0 < KPAD; k0 += 32) {
            const int kb = k0 + lkg * 8;
            short8 a0 = *reinterpret_cast<const short8*>(a_r0 + kb);
            short8 a1 = *reinterpret_cast<const short8*>(a_r1 + kb);
            short8 b0 = *reinterpret_cast<const short8*>(wr0 + kb);
            short8 b1 = *reinterpret_cast<const short8*>(wr1 + kb);
            acc[0][0] = __builtin_amdgcn_mfma_f32_16x16x32_bf16(a0, b0, acc[0][0], 0, 0, 0);
            acc[0][1] = __builtin_amdgcn_mfma_f32_16x16x32_bf16(a0, b1, acc[0][1], 0, 0, 0);
            acc[1][0] = __builtin_amdgcn_mfma_f32_16x16x32_bf16(a1, b0, acc[1][0], 0, 0, 0);
            acc[1][1] = __builtin_amdgcn_mfma_f32_16x16x32_bf16(a1, b1, acc[1][1], 0, 0, 0);
        }

        // C/D layout: col = lane&15, row = (lane>>4)*4 + reg   [m89-verified]
#pragma unroll
        for (int mi = 0; mi < 2; ++mi)
#pragma unroll
            for (int ni = 0; ni < 2; ++ni) {
                int colg = n0 + ni * 16 + lrow;
#pragma unroll
                for (int r = 0; r < 4; ++r) {
                    int rowg = m0 + mi * 16 + lkg * 4 + r;
                    unsigned short hv = f2bf(acc[mi][ni][r]);
                    if (colg < MCOLS) {
                        h1main[(size_t)rowg * MCOLS + colg] = hv;
                    } else if (colg < MCOLS + TCOLS) {
                        h1t[(size_t)rowg * TCOLS + (colg - MCOLS)] = hv;
                    }
                }
            }
    }
}

// ---------------- agg1: pull-aggregate + bias+relu+bn+relu + dot(W2) -> z ----------------
// grid-stride over nodes, one wave per node.
// Main (256 feats): half-wave (32 lanes x 16B) per row, 4 loads / 8 edges, zero-padded uniform loop.
// Tail (12 feats): all 64 lanes, lane l -> edge (l>>1), slot (l&1), from compact L2-resident h1t.
__global__ __launch_bounds__(256) void agg1_kernel(const unsigned short* __restrict__ h1main,
                                                   const unsigned short* __restrict__ h1t,
                                                   const int* __restrict__ offs,
                                                   const int* __restrict__ esrc,
                                                   const float* __restrict__ dis,
                                                   const float* __restrict__ b1,
                                                   const float* __restrict__ g1,
                                                   const float* __restrict__ beta1,
                                                   const float* __restrict__ rm1,
                                                   const float* __restrict__ rv1,
                                                   const float* __restrict__ W2,
                                                   float* __restrict__ z) {
    const int lane = threadIdx.x & 63;
    const int h  = lane >> 5;       // half 0/1
    const int sl = lane & 31;       // slot 0..31 (features sl*8..sl*8+7)
    const int wave0 = blockIdx.x * 4 + (threadIdx.x >> 6);
    const int wstride = gridDim.x * 4;
    const ushort8* mbase = reinterpret_cast<const ushort8*>(h1main);
    const ushort8* tbase = reinterpret_cast<const ushort8*>(h1t);

    for (int i = wave0; i < N_NODES; i += wstride) {
        float a[8]  = {0.f, 0.f, 0.f, 0.f, 0.f, 0.f, 0.f, 0.f};
        float tb[8] = {0.f, 0.f, 0.f, 0.f, 0.f, 0.f, 0.f, 0.f};

        const int s = offs[i], e = offs[i + 1];
        const int deg = e - s;
        const float di = dis[i];

        // self-loop main (h==0 half carries weight di, h==1 adds exact 0)
        {
            const float ws = (h == 0) ? di : 0.f;
            ushort8 v = mbase[(size_t)i * 32 + sl];
#pragma unroll
            for (int j = 0; j < 8; ++j) a[j] += ws * bf2f(v[j]);
        }
        // self-loop tail (lanes 0,1 -> slots 0,1)
        if (lane < 2) {
            ushort8 v = tbase[(size_t)i * 2 + lane];
#pragma unroll
            for (int j = 0; j < 8; ++j) tb[j] += di * bf2f(v[j]);
        }

        for (int c0 = 0; c0 < deg; c0 += 64) {
            int cnt = deg - c0; if (cnt > 64) cnt = 64;
            int   lsrc = 0;
            float lw   = 0.f;
            if (lane < cnt) {
                lsrc = esrc[s + c0 + lane];    // coalesced
                lw   = dis[lsrc];
            }
            // ---- main: 8 edges/iter (4 per half), pads contribute exact 0 ----
            const int niter = (cnt + 7) >> 3;
            for (int k = 0; k < niter; ++k) {
                int p = h + k * 8;
                int   s0 = __shfl(lsrc, p),     s1 = __shfl(lsrc, p + 2);
                int   s2 = __shfl(lsrc, p + 4), s3 = __shfl(lsrc, p + 6);
                float w0 = __shfl(lw, p),       w1 = __shfl(lw, p + 2);
                float w2 = __shfl(lw, p + 4),   w3 = __shfl(lw, p + 6);
                ushort8 v0 = mbase[(size_t)s0 * 32 + sl];
                ushort8 v1 = mbase[(size_t)s1 * 32 + sl];
                ushort8 v2 = mbase[(size_t)s2 * 32 + sl];
                ushort8 v3 = mbase[(size_t)s3 * 32 + sl];
#pragma unroll
                for (int j = 0; j < 8; ++j)
                    a[j] += w0 * bf2f(v0[j]) + w1 * bf2f(v1[j]) + w2 * bf2f(v2[j]) + w3 * bf2f(v3[j]);
            }
            // ---- tail: 32 edges/iter, lane l -> edge (l>>1), slot (l&1) ----
            const int tniter = (cnt + 31) >> 5;
            for (int k = 0; k < tniter; ++k) {
                int ei = k * 32 + (lane >> 1);
                int   ts = __shfl(lsrc, ei);
                float tw = __shfl(lw, ei);
                ushort8 v = tbase[(size_t)ts * 2 + (lane & 1)];
#pragma unroll
                for (int j = 0; j < 8; ++j) tb[j] += tw * bf2f(v[j]);
            }
        }

        // merge halves (main)
#pragma unroll
        for (int j = 0; j < 8; ++j) a[j] += __shfl_xor(a[j], 32);
        // reduce tail across lanes sharing (lane&1)
#pragma unroll
        for (int j = 0; j < 8; ++j) {
            tb[j] += __shfl_xor(tb[j], 2);
            tb[j] += __shfl_xor(tb[j], 4);
            tb[j] += __shfl_xor(tb[j], 8);
            tb[j] += __shfl_xor(tb[j], 16);
            tb[j] += __shfl_xor(tb[j], 32);
        }

        float zp = 0.f;
        if (h == 0) {
            int f0 = sl * 8;
#pragma unroll
            for (int j = 0; j < 8; ++j) {
                int f = f0 + j;
                float v = fmaxf(di * a[j] + b1[f], 0.f);
                v = fmaxf((v - rm1[f]) * rsqrtf(rv1[f] + EPS) * g1[f] + beta1[f], 0.f);
                zp += v * W2[f];
            }
            if (sl < 2) {
                int ft0 = 256 + sl * 8;
#pragma unroll
                for (int j = 0; j < 8; ++j) {
                    int f = ft0 + j;
                    if (f < FDIM) {
                        float v = fmaxf(di * tb[j] + b1[f], 0.f);
                        v = fmaxf((v - rm1[f]) * rsqrtf(rv1[f] + EPS) * g1[f] + beta1[f], 0.f);
                        zp += v * W2[f];
                    }
                }
            }
        }
#pragma unroll
        for (int off = 32; off > 0; off >>= 1) zp += __shfl_xor(zp, off);
        if (lane == 0) z[i] = zp;
    }
}

// ---------------- agg2: 8 lanes per node; pull z + bias + bn + relu + sigmoid -> out ----------------
__global__ __launch_bounds__(256) void agg2_kernel(const float* __restrict__ z,
                                                   const int* __restrict__ offs,
                                                   const int* __restrict__ esrc,
                                                   const float* __restrict__ dis,
                                                   const float* __restrict__ b2,
                                                   const float* __restrict__ g2,
                                                   const float* __restrict__ beta2,
                                                   const float* __restrict__ rm2,
                                                   const float* __restrict__ rv2,
                                                   float* __restrict__ out) {
    int gt = blockIdx.x * blockDim.x + threadIdx.x;
    int i  = gt >> 3;          // node
    int l  = gt & 7;           // sub-lane 0..7
    if (i >= N_NODES) return;
    int s = offs[i], e = offs[i + 1];
    float acc = 0.f;
    for (int p = s + l; p < e; p += 8) {
        int s0 = esrc[p];
        acc += dis[s0] * z[s0];
    }
#pragma unroll
    for (int off = 1; off < 8; off <<= 1) acc += __shfl_xor(acc, off);
    if (l == 0) {
        float di = dis[i];
        acc += di * z[i];                 // self loop
        float pre = di * acc + b2[0];
        float v = (pre - rm2[0]) * rsqrtf(rv2[0] + EPS) * g2[0] + beta2[0];
        v = fmaxf(v, 0.f);
        out[i] = 1.f / (1.f + expf(-v));
    }
}

// ---------------- launcher ----------------
extern "C" void kernel_launch(void* const* d_in, const int* in_sizes, int n_in,
                              void* d_out, int out_size, void* d_ws, size_t ws_size,
                              hipStream_t stream) {
    const float* x     = (const float*)d_in[0];
    const int*   ei    = (const int*)d_in[1];     // [2, E]: row = ei, col = ei + E
    const float* W1    = (const float*)d_in[2];
    const float* b1    = (const float*)d_in[3];
    const float* g1    = (const float*)d_in[4];
    const float* beta1 = (const float*)d_in[5];
    const float* rm1   = (const float*)d_in[6];
    const float* rv1   = (const float*)d_in[7];
    const float* W2    = (const float*)d_in[8];
    const float* b2    = (const float*)d_in[9];
    const float* g2    = (const float*)d_in[10];
    const float* beta2 = (const float*)d_in[11];
    const float* rm2   = (const float*)d_in[12];
    const float* rv2   = (const float*)d_in[13];
    float* out = (float*)d_out;

    // workspace layout (~13 MB)
    unsigned short* wt     = (unsigned short*)d_ws;             // NPAD*KPAD
    unsigned short* h1main = wt + (size_t)NPAD * KPAD;          // N*256
    unsigned short* h1t    = h1main + (size_t)N_NODES * MCOLS;  // N*16
    float* z    = (float*)(h1t + (size_t)N_NODES * TCOLS);
    float* dis  = z + N_NODES;
    int* counts = (int*)(dis + N_NODES);
    int* offs   = counts + N_NODES;
    int* cursor = offs + N_NODES + 1;
    int* esrc   = cursor + N_NODES;
    int* bsums  = esrc + N_EDGES;                               // NB_SCAN

    const int* row = ei;
    const int* col = ei + N_EDGES;

    int eb = (N_EDGES + 255) / 256;
    prep_kernel<<<NB_CONVW + NB_SCAN, 256, 0, stream>>>(W1, wt, counts);
    count_kernel<<<eb, 256, 0, stream>>>(col, counts);
    scan1_kernel<<<NB_SCAN, 256, 0, stream>>>(counts, offs, bsums, dis);
    scan3_kernel<<<NB_SCAN, 256, 0, stream>>>(bsums, offs, cursor);
    fill_kernel<<<eb, 256, 0, stream>>>(row, col, cursor, esrc);

    gemm_mfma<<<N_NODES / 32, 512, 0, stream>>>(x, wt, h1main, h1t);

    agg1_kernel<<<2048, 256, 0, stream>>>(h1main, h1t, offs, esrc, dis,
                                          b1, g1, beta1, rm1, rv1, W2, z);
    agg2_kernel<<<(N_NODES * 8 + 255) / 256, 256, 0, stream>>>(z, offs, esrc, dis,
                                                               b2, g2, beta2, rm2, rv2, out);
}

// Round 13
// 106.412 us; speedup vs baseline: 1.2798x; 1.0346x over previous
//
#include <hip/hip_runtime.h>
#include <hip/hip_bf16.h>

#define N_NODES 20000
#define N_EDGES 300000
#define FDIM    268
#define KPAD    288   // K padded to 9*32 for mfma K-loop
#define NPAD    288   // N padded to 9*32
#define MCOLS   256   // main h1 row (bf16), 64 slots of 4
#define TCOLS   16    // tail h1 row (bf16), 4 slots of 4 (12 valid + 4 zero)
#define ASTRIDE 296   // LDS A row stride in ushort (592B: 16B-aligned, 2-way bank worst case)
#define EPS     1e-3f
#define NB_SCAN ((N_NODES + 255) / 256)   // 79
#define NB_CONVW ((NPAD * KPAD + 255) / 256)  // 324

typedef __attribute__((ext_vector_type(8))) short short8;
typedef __attribute__((ext_vector_type(4))) float f32x4;
typedef __attribute__((ext_vector_type(4))) unsigned short ushort4_t;

__device__ inline unsigned short f2bf(float f) {
    __hip_bfloat16 b = __float2bfloat16(f);   // RNE
    return *reinterpret_cast<unsigned short*>(&b);
}
__device__ inline float bf2f(unsigned short u) {
    return __uint_as_float(((unsigned int)u) << 16);
}

// ---------------- prep: zero counts (blocks >= NB_CONVW) + W1 -> W1^T bf16 (blocks < NB_CONVW) ----------------
__global__ void prep_kernel(const float* __restrict__ W1, unsigned short* __restrict__ wt,
                            int* __restrict__ counts) {
    int b = blockIdx.x;
    if (b < NB_CONVW) {
        int idx = b * 256 + threadIdx.x;
        if (idx >= NPAD * KPAD) return;
        int n = idx / KPAD, k = idx - n * KPAD;
        float v = (n < FDIM && k < FDIM) ? W1[(size_t)k * FDIM + n] : 0.f;
        wt[idx] = f2bf(v);
    } else {
        int i = (b - NB_CONVW) * 256 + threadIdx.x;
        if (i < N_NODES) counts[i] = 0;
    }
}

__global__ void count_kernel(const int* __restrict__ col, int* __restrict__ counts) {
    int e = blockIdx.x * blockDim.x + threadIdx.x;
    if (e < N_EDGES) atomicAdd(&counts[col[e]], 1);
}

// stage 1: per-block exclusive scan (256 elems/block) -> offs (no base), block sums; dis
__global__ __launch_bounds__(256) void scan1_kernel(const int* __restrict__ counts,
                                                    int* __restrict__ offs,
                                                    int* __restrict__ bsums,
                                                    float* __restrict__ dis) {
    int t = threadIdx.x;
    int i = blockIdx.x * 256 + t;
    int c = (i < N_NODES) ? counts[i] : 0;
    int lane = t & 63, w = t >> 6;
    int v = c;
#pragma unroll
    for (int off = 1; off < 64; off <<= 1) {
        int u = __shfl_up(v, off);
        if (lane >= off) v += u;
    }
    __shared__ int wsum[4];
    if (lane == 63) wsum[w] = v;
    __syncthreads();
    int wbase = 0;
#pragma unroll
    for (int k = 0; k < 4; ++k) if (k < w) wbase += wsum[k];
    int incl = v + wbase;
    if (i < N_NODES) {
        offs[i] = incl - c;                         // block-local exclusive
        dis[i]  = rsqrtf((float)(c + 1));           // +1 self-loop
    }
    if (t == 255) bsums[blockIdx.x] = incl;         // block total (padding adds 0)
}

// stage 2 (merged): each block computes its own base from bsums, adds, inits cursor
__global__ __launch_bounds__(256) void scan3_kernel(const int* __restrict__ bsums,
                                                    int* __restrict__ offs,
                                                    int* __restrict__ cursor) {
    __shared__ int red[256];
    int t = threadIdx.x;
    int b = blockIdx.x;
    red[t] = (t < NB_SCAN && t < b) ? bsums[t] : 0;
    __syncthreads();
#pragma unroll
    for (int st = 128; st > 0; st >>= 1) {
        if (t < st) red[t] += red[t + st];
        __syncthreads();
    }
    int base = red[0];
    int i = b * 256 + t;
    if (i < N_NODES) {
        int o = offs[i] + base;
        offs[i] = o;
        cursor[i] = o;
    }
    if (b == NB_SCAN - 1 && t == 0) offs[N_NODES] = base + bsums[b];
}

__global__ void fill_kernel(const int* __restrict__ row, const int* __restrict__ col,
                            int* __restrict__ cursor, int* __restrict__ esrc) {
    int e = blockIdx.x * blockDim.x + threadIdx.x;
    if (e < N_EDGES) {
        int c = col[e];
        int p = atomicAdd(&cursor[c], 1);
        esrc[p] = row[e];
    }
}

// ---------------- GEMM: bf16(x) @ wt -> h1main [N][256] + h1t [N][16] ----------------
// one block (512 thr = 8 waves) per 32-row m-strip; A staged f32->bf16 into LDS once;
// wave w owns n-tile w (wave 0 also does tile 8); 18 B-loads per tile fully unrolled.
__global__ __launch_bounds__(512) void gemm_mfma(const float* __restrict__ x,
                                                 const unsigned short* __restrict__ wt,
                                                 unsigned short* __restrict__ h1main,
                                                 unsigned short* __restrict__ h1t) {
    __shared__ unsigned short As[32 * ASTRIDE];   // 18,944 B
    const int tid = threadIdx.x;
    const int m0 = blockIdx.x * 32;

    // stage: 32 rows x 72 slots of 4 cols (268 = 67 full float4 slots; 67..71 -> zero pad)
    for (int c = tid; c < 32 * 72; c += 512) {
        int r = c / 72, s = c - r * 72;
        ushort4_t o;
        if (s < 67) {
            float4 v = *reinterpret_cast<const float4*>(x + (size_t)(m0 + r) * FDIM + s * 4);
            o[0] = f2bf(v.x); o[1] = f2bf(v.y); o[2] = f2bf(v.z); o[3] = f2bf(v.w);
        } else {
            o[0] = 0; o[1] = 0; o[2] = 0; o[3] = 0;
        }
        *reinterpret_cast<ushort4_t*>(&As[r * ASTRIDE + s * 4]) = o;
    }
    __syncthreads();

    const int lane = tid & 63;
    const int w    = tid >> 6;            // wave 0..7
    const int lrow = lane & 15;
    const int lkg  = lane >> 4;           // k-group 0..3
    const unsigned short* a_r0 = &As[lrow * ASTRIDE];
    const unsigned short* a_r1 = &As[(lrow + 16) * ASTRIDE];

    for (int nt = w; nt < 9; nt += 8) {   // wave 0: tiles {0,8}; waves 1..7: one tile
        const int n0 = nt * 32;
        f32x4 acc[2][2];
#pragma unroll
        for (int a = 0; a < 2; ++a)
#pragma unroll
            for (int b = 0; b < 2; ++b) acc[a][b] = (f32x4){0.f, 0.f, 0.f, 0.f};

        const unsigned short* wr0 = wt + (size_t)(n0 + lrow) * KPAD;
        const unsigned short* wr1 = wt + (size_t)(n0 + 16 + lrow) * KPAD;

#pragma unroll
        for (int k0 = 0; k0 < KPAD; k0 += 32) {
            const int kb = k0 + lkg * 8;
            short8 a0 = *reinterpret_cast<const short8*>(a_r0 + kb);
            short8 a1 = *reinterpret_cast<const short8*>(a_r1 + kb);
            short8 b0 = *reinterpret_cast<const short8*>(wr0 + kb);
            short8 b1 = *reinterpret_cast<const short8*>(wr1 + kb);
            acc[0][0] = __builtin_amdgcn_mfma_f32_16x16x32_bf16(a0, b0, acc[0][0], 0, 0, 0);
            acc[0][1] = __builtin_amdgcn_mfma_f32_16x16x32_bf16(a0, b1, acc[0][1], 0, 0, 0);
            acc[1][0] = __builtin_amdgcn_mfma_f32_16x16x32_bf16(a1, b0, acc[1][0], 0, 0, 0);
            acc[1][1] = __builtin_amdgcn_mfma_f32_16x16x32_bf16(a1, b1, acc[1][1], 0, 0, 0);
        }

        // C/D layout: col = lane&15, row = (lane>>4)*4 + reg   [m89-verified]
#pragma unroll
        for (int mi = 0; mi < 2; ++mi)
#pragma unroll
            for (int ni = 0; ni < 2; ++ni) {
                int colg = n0 + ni * 16 + lrow;
#pragma unroll
                for (int r = 0; r < 4; ++r) {
                    int rowg = m0 + mi * 16 + lkg * 4 + r;
                    unsigned short hv = f2bf(acc[mi][ni][r]);
                    if (colg < MCOLS) {
                        h1main[(size_t)rowg * MCOLS + colg] = hv;
                    } else if (colg < MCOLS + TCOLS) {
                        h1t[(size_t)rowg * TCOLS + (colg - MCOLS)] = hv;
                    }
                }
            }
    }
}

// ---------------- agg1: pull-aggregate + bias+relu+bn+relu + dot(W2) -> z ----------------
// grid-stride, one wave per node. FULL-WAVE per edge row: lane l holds feats 4l..4l+3
// (ushort4, 8B/lane); 8 edges -> 8 independent row loads in flight per iteration.
// Tail (12 feats = 3 ushort4 slots): lane l -> edge (l>>2), slot (l&3); 16 edges/iter.
__global__ __launch_bounds__(256) void agg1_kernel(const unsigned short* __restrict__ h1main,
                                                   const unsigned short* __restrict__ h1t,
                                                   const int* __restrict__ offs,
                                                   const int* __restrict__ esrc,
                                                   const float* __restrict__ dis,
                                                   const float* __restrict__ b1,
                                                   const float* __restrict__ g1,
                                                   const float* __restrict__ beta1,
                                                   const float* __restrict__ rm1,
                                                   const float* __restrict__ rv1,
                                                   const float* __restrict__ W2,
                                                   float* __restrict__ z) {
    const int lane = threadIdx.x & 63;
    const int wave0 = blockIdx.x * 4 + (threadIdx.x >> 6);
    const int wstride = gridDim.x * 4;
    const ushort4_t* mbase = reinterpret_cast<const ushort4_t*>(h1main);  // row stride 64
    const ushort4_t* tbase = reinterpret_cast<const ushort4_t*>(h1t);    // row stride 4
    const int tsl = lane & 3;    // tail slot
    const int tei = lane >> 2;   // tail edge sub-index

    for (int i = wave0; i < N_NODES; i += wstride) {
        float a[4]  = {0.f, 0.f, 0.f, 0.f};
        float tb[4] = {0.f, 0.f, 0.f, 0.f};

        const int s = offs[i], e = offs[i + 1];
        const int deg = e - s;
        const float di = dis[i];

        // self-loop main: lane l -> slot l
        {
            ushort4_t v = mbase[(size_t)i * 64 + lane];
#pragma unroll
            for (int j = 0; j < 4; ++j) a[j] += di * bf2f(v[j]);
        }
        // self-loop tail: lanes 0..3 -> slots 0..3 (weight only on edge-group 0)
        if (lane < 4) {
            ushort4_t v = tbase[(size_t)i * 4 + lane];
#pragma unroll
            for (int j = 0; j < 4; ++j) tb[j] += di * bf2f(v[j]);
        }

        for (int c0 = 0; c0 < deg; c0 += 64) {
            int cnt = deg - c0; if (cnt > 64) cnt = 64;
            int   lsrc = 0;
            float lw   = 0.f;
            if (lane < cnt) {
                lsrc = esrc[s + c0 + lane];    // coalesced
                lw   = dis[lsrc];
            }
            // ---- main: 8 edges/iter, 8 full-wave row loads in flight; pads add exact 0 ----
            const int niter = (cnt + 7) >> 3;
            for (int k = 0; k < niter; ++k) {
                int p = k * 8;
                int   s0 = __shfl(lsrc, p),     s1 = __shfl(lsrc, p + 1);
                int   s2 = __shfl(lsrc, p + 2), s3 = __shfl(lsrc, p + 3);
                int   s4 = __shfl(lsrc, p + 4), s5 = __shfl(lsrc, p + 5);
                int   s6 = __shfl(lsrc, p + 6), s7 = __shfl(lsrc, p + 7);
                float w0 = __shfl(lw, p),       w1 = __shfl(lw, p + 1);
                float w2 = __shfl(lw, p + 2),   w3 = __shfl(lw, p + 3);
                float w4 = __shfl(lw, p + 4),   w5 = __shfl(lw, p + 5);
                float w6 = __shfl(lw, p + 6),   w7 = __shfl(lw, p + 7);
                ushort4_t v0 = mbase[(size_t)s0 * 64 + lane];
                ushort4_t v1 = mbase[(size_t)s1 * 64 + lane];
                ushort4_t v2 = mbase[(size_t)s2 * 64 + lane];
                ushort4_t v3 = mbase[(size_t)s3 * 64 + lane];
                ushort4_t v4 = mbase[(size_t)s4 * 64 + lane];
                ushort4_t v5 = mbase[(size_t)s5 * 64 + lane];
                ushort4_t v6 = mbase[(size_t)s6 * 64 + lane];
                ushort4_t v7 = mbase[(size_t)s7 * 64 + lane];
#pragma unroll
                for (int j = 0; j < 4; ++j)
                    a[j] += w0 * bf2f(v0[j]) + w1 * bf2f(v1[j]) + w2 * bf2f(v2[j]) + w3 * bf2f(v3[j])
                          + w4 * bf2f(v4[j]) + w5 * bf2f(v5[j]) + w6 * bf2f(v6[j]) + w7 * bf2f(v7[j]);
            }
            // ---- tail: 16 edges/iter, lane l -> edge (l>>2), slot (l&3) ----
            const int tniter = (cnt + 15) >> 4;
            for (int k = 0; k < tniter; ++k) {
                int ei = k * 16 + tei;
                int   ts = __shfl(lsrc, ei);
                float tw = __shfl(lw, ei);
                ushort4_t v = tbase[(size_t)ts * 4 + tsl];
#pragma unroll
                for (int j = 0; j < 4; ++j) tb[j] += tw * bf2f(v[j]);
            }
        }

        // reduce tail across the 16 edge-groups (lanes sharing lane&3)
#pragma unroll
        for (int j = 0; j < 4; ++j) {
            tb[j] += __shfl_xor(tb[j], 4);
            tb[j] += __shfl_xor(tb[j], 8);
            tb[j] += __shfl_xor(tb[j], 16);
            tb[j] += __shfl_xor(tb[j], 32);
        }

        // epilogue: bias+relu+bn+relu+dot(W2). Main: lane l owns feats 4l..4l+3.
        float zp = 0.f;
        {
            int f0 = lane * 4;
#pragma unroll
            for (int j = 0; j < 4; ++j) {
                int f = f0 + j;
                float v = fmaxf(di * a[j] + b1[f], 0.f);
                v = fmaxf((v - rm1[f]) * rsqrtf(rv1[f] + EPS) * g1[f] + beta1[f], 0.f);
                zp += v * W2[f];
            }
        }
        if (lane < 3) {   // tail slots 0..2 = feats 256..267 exactly
            int f0 = 256 + lane * 4;
#pragma unroll
            for (int j = 0; j < 4; ++j) {
                int f = f0 + j;
                float v = fmaxf(di * tb[j] + b1[f], 0.f);
                v = fmaxf((v - rm1[f]) * rsqrtf(rv1[f] + EPS) * g1[f] + beta1[f], 0.f);
                zp += v * W2[f];
            }
        }
#pragma unroll
        for (int off = 32; off > 0; off >>= 1) zp += __shfl_xor(zp, off);
        if (lane == 0) z[i] = zp;
    }
}

// ---------------- agg2: 8 lanes per node; pull z + bias + bn + relu + sigmoid -> out ----------------
__global__ __launch_bounds__(256) void agg2_kernel(const float* __restrict__ z,
                                                   const int* __restrict__ offs,
                                                   const int* __restrict__ esrc,
                                                   const float* __restrict__ dis,
                                                   const float* __restrict__ b2,
                                                   const float* __restrict__ g2,
                                                   const float* __restrict__ beta2,
                                                   const float* __restrict__ rm2,
                                                   const float* __restrict__ rv2,
                                                   float* __restrict__ out) {
    int gt = blockIdx.x * blockDim.x + threadIdx.x;
    int i  = gt >> 3;          // node
    int l  = gt & 7;           // sub-lane 0..7
    if (i >= N_NODES) return;
    int s = offs[i], e = offs[i + 1];
    float acc = 0.f;
    for (int p = s + l; p < e; p += 8) {
        int s0 = esrc[p];
        acc += dis[s0] * z[s0];
    }
#pragma unroll
    for (int off = 1; off < 8; off <<= 1) acc += __shfl_xor(acc, off);
    if (l == 0) {
        float di = dis[i];
        acc += di * z[i];                 // self loop
        float pre = di * acc + b2[0];
        float v = (pre - rm2[0]) * rsqrtf(rv2[0] + EPS) * g2[0] + beta2[0];
        v = fmaxf(v, 0.f);
        out[i] = 1.f / (1.f + expf(-v));
    }
}

// ---------------- launcher ----------------
extern "C" void kernel_launch(void* const* d_in, const int* in_sizes, int n_in,
                              void* d_out, int out_size, void* d_ws, size_t ws_size,
                              hipStream_t stream) {
    const float* x     = (const float*)d_in[0];
    const int*   ei    = (const int*)d_in[1];     // [2, E]: row = ei, col = ei + E
    const float* W1    = (const float*)d_in[2];
    const float* b1    = (const float*)d_in[3];
    const float* g1    = (const float*)d_in[4];
    const float* beta1 = (const float*)d_in[5];
    const float* rm1   = (const float*)d_in[6];
    const float* rv1   = (const float*)d_in[7];
    const float* W2    = (const float*)d_in[8];
    const float* b2    = (const float*)d_in[9];
    const float* g2    = (const float*)d_in[10];
    const float* beta2 = (const float*)d_in[11];
    const float* rm2   = (const float*)d_in[12];
    const float* rv2   = (const float*)d_in[13];
    float* out = (float*)d_out;

    // workspace layout (~13 MB)
    unsigned short* wt     = (unsigned short*)d_ws;             // NPAD*KPAD
    unsigned short* h1main = wt + (size_t)NPAD * KPAD;          // N*256
    unsigned short* h1t    = h1main + (size_t)N_NODES * MCOLS;  // N*16
    float* z    = (float*)(h1t + (size_t)N_NODES * TCOLS);
    float* dis  = z + N_NODES;
    int* counts = (int*)(dis + N_NODES);
    int* offs   = counts + N_NODES;
    int* cursor = offs + N_NODES + 1;
    int* esrc   = cursor + N_NODES;
    int* bsums  = esrc + N_EDGES;                               // NB_SCAN

    const int* row = ei;
    const int* col = ei + N_EDGES;

    int eb = (N_EDGES + 255) / 256;
    prep_kernel<<<NB_CONVW + NB_SCAN, 256, 0, stream>>>(W1, wt, counts);
    count_kernel<<<eb, 256, 0, stream>>>(col, counts);
    scan1_kernel<<<NB_SCAN, 256, 0, stream>>>(counts, offs, bsums, dis);
    scan3_kernel<<<NB_SCAN, 256, 0, stream>>>(bsums, offs, cursor);
    fill_kernel<<<eb, 256, 0, stream>>>(row, col, cursor, esrc);

    gemm_mfma<<<N_NODES / 32, 512, 0, stream>>>(x, wt, h1main, h1t);

    agg1_kernel<<<2048, 256, 0, stream>>>(h1main, h1t, offs, esrc, dis,
                                          b1, g1, beta1, rm1, rv1, W2, z);
    agg2_kernel<<<(N_NODES * 8 + 255) / 256, 256, 0, stream>>>(z, offs, esrc, dis,
                                                               b2, g2, beta2, rm2, rv2, out);
}